// Round 4
// baseline (4269.214 us; speedup 1.0000x reference)
//
#include <hip/hip_runtime.h>

// VanillaMPNN on MI355X — round 3: W2 hoisted out of the segment sum.
// Edge kernel: x = h_s*h_d -> t = relu(x@W1+b1) -> segmented in-wave scan
// by dst -> tail lanes atomicAdd t into tagg (=hout). W1-only weight
// working set (9.2 KB) fits scalar L1. Node kernel: agg = tagg@W2 + deg*b2,
// then update MLP + residual, in place on hout.

#define NE 48

// ---------------- embed ----------------
__global__ __launch_bounds__(256) void embed_kernel(const int* __restrict__ an,
                                                    const float* __restrict__ emb,
                                                    float* __restrict__ h, int n4) {
    int i = blockIdx.x * 256 + threadIdx.x;   // over N*12 float4s
    if (i >= n4) return;
    int n = i / 12, q = i - n * 12;
    ((float4*)h)[i] = ((const float4*)emb)[an[n] * 12 + q];
}

// ---------------- CSR build ----------------
__global__ __launch_bounds__(256) void hist_kernel(const int* __restrict__ dst,
                                                   int* __restrict__ cnt, int E) {
    int e = blockIdx.x * 256 + threadIdx.x;
    if (e < E) atomicAdd(&cnt[dst[e]], 1);
}

__global__ __launch_bounds__(1024) void scan_kernel(const int* __restrict__ cnt,
                                                    int* __restrict__ offs, int N) {
    __shared__ int swave[16];
    __shared__ int s_carry;
    const int tid = threadIdx.x;
    const int lane = tid & 63, wid = tid >> 6;
    if (tid == 0) s_carry = 0;
    __syncthreads();
    for (int base = 0; base < N; base += 1024) {
        int i = base + tid;
        int orig = (i < N) ? cnt[i] : 0;
        int v = orig;
#pragma unroll
        for (int off = 1; off < 64; off <<= 1) {
            int u = __shfl_up(v, off, 64);
            if (lane >= off) v += u;
        }
        if (lane == 63) swave[wid] = v;
        __syncthreads();
        if (wid == 0) {
            int w = (lane < 16) ? swave[lane] : 0;
#pragma unroll
            for (int off = 1; off < 16; off <<= 1) {
                int u = __shfl_up(w, off, 64);
                if (lane >= off) w += u;
            }
            if (lane < 16) swave[lane] = w;
        }
        __syncthreads();
        int prefix = (wid > 0) ? swave[wid - 1] : 0;
        int total = swave[15];
        int carry = s_carry;
        if (i < N) offs[i] = carry + prefix + v - orig;   // exclusive scan
        __syncthreads();
        if (tid == 0) s_carry = carry + total;
    }
}

__global__ __launch_bounds__(256) void scatter_kernel(const int* __restrict__ src,
                                                      const int* __restrict__ dst,
                                                      int* __restrict__ offs,
                                                      int2* __restrict__ pair, int E) {
    int e = blockIdx.x * 256 + threadIdx.x;
    if (e < E) {
        int d = dst[e];
        int p = atomicAdd(&offs[d], 1);
        pair[p] = make_int2(src[e], d);   // sorted by d
    }
}

__global__ __launch_bounds__(256) void transpose_kernel(const float* __restrict__ in,
                                                        float* __restrict__ out, int total) {
    int idx = blockIdx.x * 256 + threadIdx.x;
    if (idx >= total) return;
    int m = idx / (NE * NE), r = idx - m * NE * NE;
    int i = r / NE, j = r - i * NE;
    out[m * NE * NE + j * NE + i] = in[idx];
}

// ---------------- edge: GEMM1 + relu + segmented reduce ----------------
__global__ __launch_bounds__(256) void edge_kernel(
    const float* __restrict__ hin,
    const int2* __restrict__ pair,
    float* __restrict__ tagg,                                       // == hout, pre-zeroed
    const float* __restrict__ w1t, const float* __restrict__ b1,    // W1 transposed, row k contiguous
    int E)
{
    const int p = blockIdx.x * 256 + threadIdx.x;
    const int lane = threadIdx.x & 63;
    const bool valid = (p < E);
    int2 sd = pair[valid ? p : (E - 1)];
    const int s = sd.x;
    const int d = valid ? sd.y : -1;    // -1: never merges, never emits

    const float4* hs4 = (const float4*)(hin + (size_t)s * NE);
    const float4* hd4 = (const float4*)(hin + (size_t)sd.y * NE);
    float x[NE];
#pragma unroll
    for (int q = 0; q < 12; ++q) {
        float4 a = hs4[q], b = hd4[q];
        x[4*q+0] = a.x * b.x; x[4*q+1] = a.y * b.y;
        x[4*q+2] = a.z * b.z; x[4*q+3] = a.w * b.w;
    }

    // segment flags (once)
    int dn = __shfl_down(d, 1, 64);
    const bool tail = (lane == 63) || (dn != d);
    bool f[6];
#pragma unroll
    for (int i = 0; i < 6; ++i) {
        int off = 1 << i;
        int dp = __shfl_up(d, off, 64);
        f[i] = (lane >= off) && (dp == d);
    }

    // t[k] = relu(x . W1[:,k] + b1[k])
    float t[NE];
    const float4* W1 = (const float4*)w1t;   // [48][12]
#pragma unroll 3
    for (int k = 0; k < NE; ++k) {
        float t0 = b1[k], t1 = 0.0f, t2 = 0.0f, t3 = 0.0f;
#pragma unroll
        for (int q = 0; q < 12; ++q) {
            float4 w = W1[k * 12 + q];
            t0 = fmaf(x[4*q+0], w.x, t0);
            t1 = fmaf(x[4*q+1], w.y, t1);
            t2 = fmaf(x[4*q+2], w.z, t2);
            t3 = fmaf(x[4*q+3], w.w, t3);
        }
        float tv = fmaxf((t0 + t1) + (t2 + t3), 0.0f);
        t[k] = valid ? tv : 0.0f;
    }

    // in-wave inclusive segmented scan keyed on d (sorted within wave)
#pragma unroll
    for (int i = 0; i < 6; ++i) {
        int off = 1 << i;
#pragma unroll
        for (int j = 0; j < NE; ++j) {
            float tu = __shfl_up(t[j], off, 64);
            t[j] += f[i] ? tu : 0.0f;
        }
    }

    if (valid && tail) {
        float* ap = tagg + (size_t)d * NE;
#pragma unroll
        for (int j = 0; j < NE; ++j) atomicAdd(ap + j, t[j]);
    }
}

// ---------------- node: W2 GEMV + update MLP (in place on hout) ----------------
__global__ __launch_bounds__(256) void node_kernel(
    const float* __restrict__ hin,
    float* __restrict__ hout,                                       // holds tagg on entry
    const int* __restrict__ cnt,
    const float* __restrict__ w2,  const float* __restrict__ b2,    // msg W2 row-major, msg b2
    const float* __restrict__ u1t, const float* __restrict__ ub1,   // U1 transposed
    const float* __restrict__ u2,  const float* __restrict__ ub2,   // U2 row-major
    int N)
{
    int n = blockIdx.x * 256 + threadIdx.x;
    if (n >= N) return;

    float tg[NE];
    const float4* ag = (const float4*)(hout + (size_t)n * NE);
#pragma unroll
    for (int q = 0; q < 12; ++q) {
        float4 a = ag[q];
        tg[4*q+0] = a.x; tg[4*q+1] = a.y; tg[4*q+2] = a.z; tg[4*q+3] = a.w;
    }

    // agg = tagg @ W2 + deg * b2
    float fdeg = (float)cnt[n];
    float acc[NE];
#pragma unroll
    for (int q = 0; q < 12; ++q) {
        float4 b = ((const float4*)b2)[q];
        acc[4*q+0] = fdeg * b.x; acc[4*q+1] = fdeg * b.y;
        acc[4*q+2] = fdeg * b.z; acc[4*q+3] = fdeg * b.w;
    }
    const float4* W2 = (const float4*)w2;    // [48][12], row k contiguous
#pragma unroll 3
    for (int k = 0; k < NE; ++k) {
        float tv = tg[k];
#pragma unroll
        for (int q = 0; q < 12; ++q) {
            float4 w = W2[k * 12 + q];
            acc[4*q+0] = fmaf(tv, w.x, acc[4*q+0]);
            acc[4*q+1] = fmaf(tv, w.y, acc[4*q+1]);
            acc[4*q+2] = fmaf(tv, w.z, acc[4*q+2]);
            acc[4*q+3] = fmaf(tv, w.w, acc[4*q+3]);
        }
    }

    // out = hin + ub2 + sum_k relu(acc . U1[:,k] + ub1[k]) * U2[k,:]
    float outv[NE];
    const float4* hp = (const float4*)(hin + (size_t)n * NE);
#pragma unroll
    for (int q = 0; q < 12; ++q) {
        float4 a = hp[q];
        float4 b = ((const float4*)ub2)[q];
        outv[4*q+0] = a.x + b.x; outv[4*q+1] = a.y + b.y;
        outv[4*q+2] = a.z + b.z; outv[4*q+3] = a.w + b.w;
    }
    const float4* U1 = (const float4*)u1t;
    const float4* U2 = (const float4*)u2;
#pragma unroll 3
    for (int k = 0; k < NE; ++k) {
        float t0 = ub1[k], t1 = 0.0f, t2 = 0.0f, t3 = 0.0f;
#pragma unroll
        for (int q = 0; q < 12; ++q) {
            float4 w = U1[k * 12 + q];
            t0 = fmaf(acc[4*q+0], w.x, t0);
            t1 = fmaf(acc[4*q+1], w.y, t1);
            t2 = fmaf(acc[4*q+2], w.z, t2);
            t3 = fmaf(acc[4*q+3], w.w, t3);
        }
        float t = fmaxf((t0 + t1) + (t2 + t3), 0.0f);
#pragma unroll
        for (int q = 0; q < 12; ++q) {
            float4 w = U2[k * 12 + q];
            outv[4*q+0] = fmaf(t, w.x, outv[4*q+0]);
            outv[4*q+1] = fmaf(t, w.y, outv[4*q+1]);
            outv[4*q+2] = fmaf(t, w.z, outv[4*q+2]);
            outv[4*q+3] = fmaf(t, w.w, outv[4*q+3]);
        }
    }

    float4* ho = (float4*)(hout + (size_t)n * NE);
#pragma unroll
    for (int q = 0; q < 12; ++q)
        ho[q] = make_float4(outv[4*q+0], outv[4*q+1], outv[4*q+2], outv[4*q+3]);
}

// ---------------- readout ----------------
__global__ __launch_bounds__(256) void readout_kernel(const float* __restrict__ h,
                                                      const int* __restrict__ gid,
                                                      const float* __restrict__ w1t,
                                                      const float* __restrict__ b1,
                                                      const float* __restrict__ w2,   // [48]
                                                      const float* __restrict__ b2,   // [1]
                                                      float* __restrict__ out, int N) {
    int n = blockIdx.x * 256 + threadIdx.x;
    if (n >= N) return;
    float x[NE];
    const float4* hp = (const float4*)(h + (size_t)n * NE);
#pragma unroll
    for (int q = 0; q < 12; ++q) {
        float4 a = hp[q];
        x[4*q+0] = a.x; x[4*q+1] = a.y; x[4*q+2] = a.z; x[4*q+3] = a.w;
    }
    const float4* W1 = (const float4*)w1t;
    float y = b2[0];
#pragma unroll 3
    for (int k = 0; k < NE; ++k) {
        float t0 = b1[k], t1 = 0.0f, t2 = 0.0f, t3 = 0.0f;
#pragma unroll
        for (int q = 0; q < 12; ++q) {
            float4 w = W1[k * 12 + q];
            t0 = fmaf(x[4*q+0], w.x, t0);
            t1 = fmaf(x[4*q+1], w.y, t1);
            t2 = fmaf(x[4*q+2], w.z, t2);
            t3 = fmaf(x[4*q+3], w.w, t3);
        }
        float t = fmaxf((t0 + t1) + (t2 + t3), 0.0f);
        y = fmaf(t, w2[k], y);
    }
    atomicAdd(out + gid[n], y);
}

extern "C" void kernel_launch(void* const* d_in, const int* in_sizes, int n_in,
                              void* d_out, int out_size, void* d_ws, size_t ws_size,
                              hipStream_t stream) {
    const int*   AtomicNum = (const int*)  d_in[0];
    const int*   Edge      = (const int*)  d_in[1];
    const int*   graph_id  = (const int*)  d_in[2];
    const float* emb       = (const float*)d_in[3];
    const float* msg_w1    = (const float*)d_in[4];
    const float* msg_b1    = (const float*)d_in[5];
    const float* msg_w2    = (const float*)d_in[6];
    const float* msg_b2    = (const float*)d_in[7];
    const float* upd_w1    = (const float*)d_in[8];
    const float* upd_b1    = (const float*)d_in[9];
    const float* upd_w2    = (const float*)d_in[10];
    const float* upd_b2    = (const float*)d_in[11];
    const float* ro_w1     = (const float*)d_in[12];
    const float* ro_b1     = (const float*)d_in[13];
    const float* ro_w2     = (const float*)d_in[14];
    const float* ro_b2     = (const float*)d_in[15];

    const int N = in_sizes[0];          // 100000
    const int E = in_sizes[1] / 2;      // 1600000
    const int* src = Edge;
    const int* dst = Edge + E;

    // workspace layout (~52 MB)
    float* h    = (float*)d_ws;                    // N*48
    float* h2   = h  + (size_t)N * NE;             // N*48
    float* w1t  = h2 + (size_t)N * NE;             // 6*2304
    float* u1t  = w1t + 6 * NE * NE;               // 6*2304
    float* rw1t = u1t + 6 * NE * NE;               // 2304
    int*   cnt    = (int*)(rw1t + NE * NE);        // N
    int*   offs   = cnt + N;                       // N
    int2*  pair   = (int2*)(offs + N);             // E (src,dst) sorted by dst

    hipMemsetAsync(d_out, 0, (size_t)out_size * sizeof(float), stream);
    hipMemsetAsync(cnt, 0, (size_t)N * sizeof(int), stream);

    int n4 = N * 12;
    embed_kernel<<<(n4 + 255) / 256, 256, 0, stream>>>(AtomicNum, emb, h, n4);

    hist_kernel<<<(E + 255) / 256, 256, 0, stream>>>(dst, cnt, E);
    scan_kernel<<<1, 1024, 0, stream>>>(cnt, offs, N);
    scatter_kernel<<<(E + 255) / 256, 256, 0, stream>>>(src, dst, offs, pair, E);

    transpose_kernel<<<(6 * NE * NE + 255) / 256, 256, 0, stream>>>(msg_w1, w1t, 6 * NE * NE);
    transpose_kernel<<<(6 * NE * NE + 255) / 256, 256, 0, stream>>>(upd_w1, u1t, 6 * NE * NE);
    transpose_kernel<<<(NE * NE + 255) / 256, 256, 0, stream>>>(ro_w1, rw1t, NE * NE);

    const float* hin = h;
    float* hout = h2;
    for (int l = 0; l < 6; ++l) {
        hipMemsetAsync(hout, 0, (size_t)N * NE * sizeof(float), stream);
        edge_kernel<<<(E + 255) / 256, 256, 0, stream>>>(
            hin, pair, hout,
            w1t + (size_t)l * NE * NE, msg_b1 + (size_t)l * NE,
            E);
        node_kernel<<<(N + 255) / 256, 256, 0, stream>>>(
            hin, hout, cnt,
            msg_w2 + (size_t)l * NE * NE, msg_b2 + (size_t)l * NE,
            u1t + (size_t)l * NE * NE, upd_b1 + (size_t)l * NE,
            upd_w2 + (size_t)l * NE * NE, upd_b2 + (size_t)l * NE,
            N);
        const float* tmp = hin; hin = hout; hout = (float*)tmp;
    }

    readout_kernel<<<(N + 255) / 256, 256, 0, stream>>>(
        hin, graph_id, rw1t, ro_b1, ro_w2, ro_b2, (float*)d_out, N);
}

// Round 5
// 3377.362 us; speedup vs baseline: 1.2641x; 1.2641x over previous
//
#include <hip/hip_runtime.h>

// VanillaMPNN on MI355X — round 4: spill-free k-outer/j-inner GEMVs.
// Round-3 post-mortem: j-outer dot formulation kept x[48]+t[48] live ->
// scratch spills (~1.1 GB/dispatch HBM traffic). Fix: t[j] += x[k]*W1[k][j]
// with W1 row-major (original layout, no transpose), x streamed float4-wise
// from the h_s/h_d gathers. Only one 48-float accumulator array live.
// W2 stays hoisted out of the segment sum (round-3 algebra, FLOPs halved).

#define NE 48

// ---------------- embed ----------------
__global__ __launch_bounds__(256) void embed_kernel(const int* __restrict__ an,
                                                    const float* __restrict__ emb,
                                                    float* __restrict__ h, int n4) {
    int i = blockIdx.x * 256 + threadIdx.x;   // over N*12 float4s
    if (i >= n4) return;
    int n = i / 12, q = i - n * 12;
    ((float4*)h)[i] = ((const float4*)emb)[an[n] * 12 + q];
}

// ---------------- CSR build ----------------
__global__ __launch_bounds__(256) void hist_kernel(const int* __restrict__ dst,
                                                   int* __restrict__ cnt, int E) {
    int e = blockIdx.x * 256 + threadIdx.x;
    if (e < E) atomicAdd(&cnt[dst[e]], 1);
}

__global__ __launch_bounds__(1024) void scan_kernel(const int* __restrict__ cnt,
                                                    int* __restrict__ offs, int N) {
    __shared__ int swave[16];
    __shared__ int s_carry;
    const int tid = threadIdx.x;
    const int lane = tid & 63, wid = tid >> 6;
    if (tid == 0) s_carry = 0;
    __syncthreads();
    for (int base = 0; base < N; base += 1024) {
        int i = base + tid;
        int orig = (i < N) ? cnt[i] : 0;
        int v = orig;
#pragma unroll
        for (int off = 1; off < 64; off <<= 1) {
            int u = __shfl_up(v, off, 64);
            if (lane >= off) v += u;
        }
        if (lane == 63) swave[wid] = v;
        __syncthreads();
        if (wid == 0) {
            int w = (lane < 16) ? swave[lane] : 0;
#pragma unroll
            for (int off = 1; off < 16; off <<= 1) {
                int u = __shfl_up(w, off, 64);
                if (lane >= off) w += u;
            }
            if (lane < 16) swave[lane] = w;
        }
        __syncthreads();
        int prefix = (wid > 0) ? swave[wid - 1] : 0;
        int total = swave[15];
        int carry = s_carry;
        if (i < N) offs[i] = carry + prefix + v - orig;   // exclusive scan
        __syncthreads();
        if (tid == 0) s_carry = carry + total;
    }
}

__global__ __launch_bounds__(256) void scatter_kernel(const int* __restrict__ src,
                                                      const int* __restrict__ dst,
                                                      int* __restrict__ offs,
                                                      int2* __restrict__ pair, int E) {
    int e = blockIdx.x * 256 + threadIdx.x;
    if (e < E) {
        int d = dst[e];
        int p = atomicAdd(&offs[d], 1);
        pair[p] = make_int2(src[e], d);   // sorted by d
    }
}

// ---------------- edge: GEMM1 + relu + segmented reduce ----------------
__global__ __launch_bounds__(256) void edge_kernel(
    const float* __restrict__ hin,
    const int2* __restrict__ pair,
    float* __restrict__ tagg,                                      // == hout, pre-zeroed
    const float* __restrict__ w1, const float* __restrict__ b1,    // W1 row-major [k][j]
    int E)
{
    const int p = blockIdx.x * 256 + threadIdx.x;
    const int lane = threadIdx.x & 63;
    const bool valid = (p < E);
    int2 sd = pair[valid ? p : (E - 1)];
    const int s = sd.x;
    const int d = valid ? sd.y : -1;    // -1: never merges, never emits

    const float4* hs4 = (const float4*)(hin + (size_t)s * NE);
    const float4* hd4 = (const float4*)(hin + (size_t)sd.y * NE);

    // t[j] = b1[j]; accumulate t[j] += x[k] * W1[k][j], x streamed
    float t[NE];
#pragma unroll
    for (int q = 0; q < 12; ++q) {
        float4 b = ((const float4*)b1)[q];
        t[4*q+0] = b.x; t[4*q+1] = b.y; t[4*q+2] = b.z; t[4*q+3] = b.w;
    }

    const float4* W1 = (const float4*)w1;   // [48][12], row k contiguous
    float4 a = hs4[0], c = hd4[0];
#pragma unroll
    for (int q = 0; q < 12; ++q) {
        float4 an, cn;
        if (q < 11) { an = hs4[q + 1]; cn = hd4[q + 1]; }   // prefetch next chunk
        float xv0 = a.x * c.x, xv1 = a.y * c.y, xv2 = a.z * c.z, xv3 = a.w * c.w;
#pragma unroll
        for (int kk = 0; kk < 4; ++kk) {
            const float xk = (kk == 0) ? xv0 : (kk == 1) ? xv1 : (kk == 2) ? xv2 : xv3;
            const int k = 4 * q + kk;
#pragma unroll
            for (int j = 0; j < 12; ++j) {
                float4 w = W1[k * 12 + j];                  // wave-uniform -> s_load
                t[4*j+0] = fmaf(xk, w.x, t[4*j+0]);
                t[4*j+1] = fmaf(xk, w.y, t[4*j+1]);
                t[4*j+2] = fmaf(xk, w.z, t[4*j+2]);
                t[4*j+3] = fmaf(xk, w.w, t[4*j+3]);
            }
        }
        a = an; c = cn;
    }
#pragma unroll
    for (int j = 0; j < NE; ++j) {
        float tv = fmaxf(t[j], 0.0f);
        t[j] = valid ? tv : 0.0f;
    }

    // in-wave inclusive segmented scan keyed on d (sorted within wave)
    int dn = __shfl_down(d, 1, 64);
    const bool tail = (lane == 63) || (dn != d);
#pragma unroll
    for (int i = 0; i < 6; ++i) {
        int off = 1 << i;
        int dp = __shfl_up(d, off, 64);
        bool f = (lane >= off) && (dp == d);
        if (__any(f)) {
#pragma unroll
            for (int j = 0; j < NE; ++j) {
                float tu = __shfl_up(t[j], off, 64);
                t[j] += f ? tu : 0.0f;
            }
        }
    }

    if (valid && tail) {
        float* ap = tagg + (size_t)d * NE;
#pragma unroll
        for (int j = 0; j < NE; ++j) atomicAdd(ap + j, t[j]);
    }
}

// ---------------- node: W2 GEMV + update MLP (in place on hout) ----------------
__global__ __launch_bounds__(256, 2) void node_kernel(
    const float* __restrict__ hin,
    float* __restrict__ hout,                                      // holds tagg on entry
    const int* __restrict__ cnt,
    const float* __restrict__ w2, const float* __restrict__ b2,    // msg W2 row-major, msg b2
    const float* __restrict__ u1, const float* __restrict__ ub1,   // U1 row-major
    const float* __restrict__ u2, const float* __restrict__ ub2,   // U2 row-major
    int N)
{
    int n = blockIdx.x * 256 + threadIdx.x;
    if (n >= N) return;

    // acc[j] = deg*b2[j] + sum_k tagg[k] * W2[k][j]   (tagg streamed)
    float fdeg = (float)cnt[n];
    float acc[NE];
#pragma unroll
    for (int q = 0; q < 12; ++q) {
        float4 b = ((const float4*)b2)[q];
        acc[4*q+0] = fdeg * b.x; acc[4*q+1] = fdeg * b.y;
        acc[4*q+2] = fdeg * b.z; acc[4*q+3] = fdeg * b.w;
    }
    const float4* tg4 = (const float4*)(hout + (size_t)n * NE);
    const float4* W2 = (const float4*)w2;
    {
        float4 g = tg4[0];
#pragma unroll
        for (int q = 0; q < 12; ++q) {
            float4 gn;
            if (q < 11) gn = tg4[q + 1];
            float g0 = g.x, g1 = g.y, g2 = g.z, g3 = g.w;
#pragma unroll
            for (int kk = 0; kk < 4; ++kk) {
                const float gk = (kk == 0) ? g0 : (kk == 1) ? g1 : (kk == 2) ? g2 : g3;
                const int k = 4 * q + kk;
#pragma unroll
                for (int j = 0; j < 12; ++j) {
                    float4 w = W2[k * 12 + j];
                    acc[4*j+0] = fmaf(gk, w.x, acc[4*j+0]);
                    acc[4*j+1] = fmaf(gk, w.y, acc[4*j+1]);
                    acc[4*j+2] = fmaf(gk, w.z, acc[4*j+2]);
                    acc[4*j+3] = fmaf(gk, w.w, acc[4*j+3]);
                }
            }
            g = gn;
        }
    }

    // t[j] = relu(ub1[j] + sum_k acc[k]*U1[k][j])
    float t[NE];
#pragma unroll
    for (int q = 0; q < 12; ++q) {
        float4 b = ((const float4*)ub1)[q];
        t[4*q+0] = b.x; t[4*q+1] = b.y; t[4*q+2] = b.z; t[4*q+3] = b.w;
    }
    const float4* U1 = (const float4*)u1;
#pragma unroll
    for (int k = 0; k < NE; ++k) {
        const float ak = acc[k];
#pragma unroll
        for (int j = 0; j < 12; ++j) {
            float4 w = U1[k * 12 + j];
            t[4*j+0] = fmaf(ak, w.x, t[4*j+0]);
            t[4*j+1] = fmaf(ak, w.y, t[4*j+1]);
            t[4*j+2] = fmaf(ak, w.z, t[4*j+2]);
            t[4*j+3] = fmaf(ak, w.w, t[4*j+3]);
        }
    }
#pragma unroll
    for (int j = 0; j < NE; ++j) t[j] = fmaxf(t[j], 0.0f);

    // out[j] = hin[j] + ub2[j] + sum_k t[k]*U2[k][j]   (reuse acc as out)
    const float4* hp = (const float4*)(hin + (size_t)n * NE);
#pragma unroll
    for (int q = 0; q < 12; ++q) {
        float4 a = hp[q];
        float4 b = ((const float4*)ub2)[q];
        acc[4*q+0] = a.x + b.x; acc[4*q+1] = a.y + b.y;
        acc[4*q+2] = a.z + b.z; acc[4*q+3] = a.w + b.w;
    }
    const float4* U2 = (const float4*)u2;
#pragma unroll
    for (int k = 0; k < NE; ++k) {
        const float tk = t[k];
#pragma unroll
        for (int j = 0; j < 12; ++j) {
            float4 w = U2[k * 12 + j];
            acc[4*j+0] = fmaf(tk, w.x, acc[4*j+0]);
            acc[4*j+1] = fmaf(tk, w.y, acc[4*j+1]);
            acc[4*j+2] = fmaf(tk, w.z, acc[4*j+2]);
            acc[4*j+3] = fmaf(tk, w.w, acc[4*j+3]);
        }
    }

    float4* ho = (float4*)(hout + (size_t)n * NE);
#pragma unroll
    for (int q = 0; q < 12; ++q)
        ho[q] = make_float4(acc[4*q+0], acc[4*q+1], acc[4*q+2], acc[4*q+3]);
}

// ---------------- readout ----------------
__global__ __launch_bounds__(256, 2) void readout_kernel(const float* __restrict__ h,
                                                         const int* __restrict__ gid,
                                                         const float* __restrict__ w1,  // row-major
                                                         const float* __restrict__ b1,
                                                         const float* __restrict__ w2,  // [48]
                                                         const float* __restrict__ b2,  // [1]
                                                         float* __restrict__ out, int N) {
    int n = blockIdx.x * 256 + threadIdx.x;
    if (n >= N) return;

    float t[NE];
#pragma unroll
    for (int q = 0; q < 12; ++q) {
        float4 b = ((const float4*)b1)[q];
        t[4*q+0] = b.x; t[4*q+1] = b.y; t[4*q+2] = b.z; t[4*q+3] = b.w;
    }
    const float4* hp = (const float4*)(h + (size_t)n * NE);
    const float4* W1 = (const float4*)w1;
    {
        float4 a = hp[0];
#pragma unroll
        for (int q = 0; q < 12; ++q) {
            float4 an;
            if (q < 11) an = hp[q + 1];
            float a0 = a.x, a1 = a.y, a2 = a.z, a3 = a.w;
#pragma unroll
            for (int kk = 0; kk < 4; ++kk) {
                const float xk = (kk == 0) ? a0 : (kk == 1) ? a1 : (kk == 2) ? a2 : a3;
                const int k = 4 * q + kk;
#pragma unroll
                for (int j = 0; j < 12; ++j) {
                    float4 w = W1[k * 12 + j];
                    t[4*j+0] = fmaf(xk, w.x, t[4*j+0]);
                    t[4*j+1] = fmaf(xk, w.y, t[4*j+1]);
                    t[4*j+2] = fmaf(xk, w.z, t[4*j+2]);
                    t[4*j+3] = fmaf(xk, w.w, t[4*j+3]);
                }
            }
            a = an;
        }
    }
    float y = b2[0];
#pragma unroll
    for (int j = 0; j < NE; ++j) y = fmaf(fmaxf(t[j], 0.0f), w2[j], y);
    atomicAdd(out + gid[n], y);
}

extern "C" void kernel_launch(void* const* d_in, const int* in_sizes, int n_in,
                              void* d_out, int out_size, void* d_ws, size_t ws_size,
                              hipStream_t stream) {
    const int*   AtomicNum = (const int*)  d_in[0];
    const int*   Edge      = (const int*)  d_in[1];
    const int*   graph_id  = (const int*)  d_in[2];
    const float* emb       = (const float*)d_in[3];
    const float* msg_w1    = (const float*)d_in[4];
    const float* msg_b1    = (const float*)d_in[5];
    const float* msg_w2    = (const float*)d_in[6];
    const float* msg_b2    = (const float*)d_in[7];
    const float* upd_w1    = (const float*)d_in[8];
    const float* upd_b1    = (const float*)d_in[9];
    const float* upd_w2    = (const float*)d_in[10];
    const float* upd_b2    = (const float*)d_in[11];
    const float* ro_w1     = (const float*)d_in[12];
    const float* ro_b1     = (const float*)d_in[13];
    const float* ro_w2     = (const float*)d_in[14];
    const float* ro_b2     = (const float*)d_in[15];

    const int N = in_sizes[0];          // 100000
    const int E = in_sizes[1] / 2;      // 1600000
    const int* src = Edge;
    const int* dst = Edge + E;

    // workspace layout (~52 MB)
    float* h    = (float*)d_ws;                    // N*48
    float* h2   = h  + (size_t)N * NE;             // N*48
    int*   cnt    = (int*)(h2 + (size_t)N * NE);   // N
    int*   offs   = cnt + N;                       // N
    int2*  pair   = (int2*)(offs + N);             // E (src,dst) sorted by dst

    hipMemsetAsync(d_out, 0, (size_t)out_size * sizeof(float), stream);
    hipMemsetAsync(cnt, 0, (size_t)N * sizeof(int), stream);

    int n4 = N * 12;
    embed_kernel<<<(n4 + 255) / 256, 256, 0, stream>>>(AtomicNum, emb, h, n4);

    hist_kernel<<<(E + 255) / 256, 256, 0, stream>>>(dst, cnt, E);
    scan_kernel<<<1, 1024, 0, stream>>>(cnt, offs, N);
    scatter_kernel<<<(E + 255) / 256, 256, 0, stream>>>(src, dst, offs, pair, E);

    const float* hin = h;
    float* hout = h2;
    for (int l = 0; l < 6; ++l) {
        hipMemsetAsync(hout, 0, (size_t)N * NE * sizeof(float), stream);
        edge_kernel<<<(E + 255) / 256, 256, 0, stream>>>(
            hin, pair, hout,
            msg_w1 + (size_t)l * NE * NE, msg_b1 + (size_t)l * NE,
            E);
        node_kernel<<<(N + 255) / 256, 256, 0, stream>>>(
            hin, hout, cnt,
            msg_w2 + (size_t)l * NE * NE, msg_b2 + (size_t)l * NE,
            upd_w1 + (size_t)l * NE * NE, upd_b1 + (size_t)l * NE,
            upd_w2 + (size_t)l * NE * NE, upd_b2 + (size_t)l * NE,
            N);
        const float* tmp = hin; hin = hout; hout = (float*)tmp;
    }

    readout_kernel<<<(N + 255) / 256, 256, 0, stream>>>(
        hin, graph_id, ro_w1, ro_b1, ro_w2, ro_b2, (float*)d_out, N);
}

// Round 6
// 2918.795 us; speedup vs baseline: 1.4627x; 1.1571x over previous
//
#include <hip/hip_runtime.h>

// VanillaMPNN on MI355X — round 5: scan-free edge reduction.
// Edge kernel: per-lane gather + k-outer GEMM (2 j-chunks of 24), then
// per-wave LDS tile t[j][e] ([24][65] pad -> conflict-free both phases);
// lanes 0-23 / 32-55 sequentially reduce e=0..31 / 32..63 per dim with
// flush-on-boundary (ballot bitmask) via coalesced 24-lane atomicAdd.
// Removes the 6-stage shfl scan (288 bpermute) and the 48-instr tail-lane
// atomic storm. W2 stays hoisted (round-3 algebra).

#define NE 48
#define TJ 24

// ---------------- embed ----------------
__global__ __launch_bounds__(256) void embed_kernel(const int* __restrict__ an,
                                                    const float* __restrict__ emb,
                                                    float* __restrict__ h, int n4) {
    int i = blockIdx.x * 256 + threadIdx.x;   // over N*12 float4s
    if (i >= n4) return;
    int n = i / 12, q = i - n * 12;
    ((float4*)h)[i] = ((const float4*)emb)[an[n] * 12 + q];
}

// ---------------- CSR build ----------------
__global__ __launch_bounds__(256) void hist_kernel(const int* __restrict__ dst,
                                                   int* __restrict__ cnt, int E) {
    int e = blockIdx.x * 256 + threadIdx.x;
    if (e < E) atomicAdd(&cnt[dst[e]], 1);
}

__global__ __launch_bounds__(1024) void scan_kernel(const int* __restrict__ cnt,
                                                    int* __restrict__ offs, int N) {
    __shared__ int swave[16];
    __shared__ int s_carry;
    const int tid = threadIdx.x;
    const int lane = tid & 63, wid = tid >> 6;
    if (tid == 0) s_carry = 0;
    __syncthreads();
    for (int base = 0; base < N; base += 1024) {
        int i = base + tid;
        int orig = (i < N) ? cnt[i] : 0;
        int v = orig;
#pragma unroll
        for (int off = 1; off < 64; off <<= 1) {
            int u = __shfl_up(v, off, 64);
            if (lane >= off) v += u;
        }
        if (lane == 63) swave[wid] = v;
        __syncthreads();
        if (wid == 0) {
            int w = (lane < 16) ? swave[lane] : 0;
#pragma unroll
            for (int off = 1; off < 16; off <<= 1) {
                int u = __shfl_up(w, off, 64);
                if (lane >= off) w += u;
            }
            if (lane < 16) swave[lane] = w;
        }
        __syncthreads();
        int prefix = (wid > 0) ? swave[wid - 1] : 0;
        int total = swave[15];
        int carry = s_carry;
        if (i < N) offs[i] = carry + prefix + v - orig;   // exclusive scan
        __syncthreads();
        if (tid == 0) s_carry = carry + total;
    }
}

__global__ __launch_bounds__(256) void scatter_kernel(const int* __restrict__ src,
                                                      const int* __restrict__ dst,
                                                      int* __restrict__ offs,
                                                      int2* __restrict__ pair, int E) {
    int e = blockIdx.x * 256 + threadIdx.x;
    if (e < E) {
        int d = dst[e];
        int p = atomicAdd(&offs[d], 1);
        pair[p] = make_int2(src[e], d);   // sorted by d
    }
}

// ---------------- edge: GEMM1 + relu + LDS-transposed segment reduce ----------------
__global__ __launch_bounds__(256) void edge_kernel(
    const float* __restrict__ hin,
    const int2* __restrict__ pair,
    float* __restrict__ tagg,                                      // == hout, pre-zeroed
    const float* __restrict__ w1, const float* __restrict__ b1,    // W1 row-major [k][j]
    int E)
{
    __shared__ float s_t[4][TJ][65];   // [wave][j][e] (+1 pad: both phases conflict-free)
    __shared__ int   s_d[4][64];

    const int p = blockIdx.x * 256 + threadIdx.x;
    const int lane = threadIdx.x & 63;
    const int wid  = threadIdx.x >> 6;
    const bool valid = (p < E);
    int2 sd = pair[valid ? p : (E - 1)];
    const int d = valid ? sd.y : -1;    // -1: discarded at flush

    s_d[wid][lane] = d;

    // segment-boundary bitmask (bit e = segment ends at lane e)
    int dn = __shfl_down(d, 1, 64);
    bool tailf = (lane == 63) || (dn != d);
    unsigned long long bm = __ballot(tailf);

    // gather x = h_src * h_dst (one shot; 24 independent dwordx4 loads)
    float x[NE];
    {
        const float4* hs4 = (const float4*)(hin + (size_t)sd.x * NE);
        const float4* hd4 = (const float4*)(hin + (size_t)sd.y * NE);
#pragma unroll
        for (int q = 0; q < 12; ++q) {
            float4 a = hs4[q], c = hd4[q];
            x[4*q+0] = a.x * c.x; x[4*q+1] = a.y * c.y;
            x[4*q+2] = a.z * c.z; x[4*q+3] = a.w * c.w;
        }
    }

    // reducer role: lanes 0-23 cover e=0..31, lanes 32-55 cover e=32..63
    const int jr    = (lane < 32) ? lane : (lane - 32);
    const int ebase = (lane < 32) ? 0 : 32;
    const bool ract = (jr < TJ);
    const unsigned int bhalf = (unsigned int)(bm >> ebase) | 0x80000000u;  // force flush at range end

    const float4* W = (const float4*)w1;   // [48][12] float4, row k contiguous

#pragma unroll 1
    for (int jh = 0; jh < 2; ++jh) {
        // ---- GEMM chunk: t[j] = b1[jh*24+j] + sum_k x[k]*W1[k][jh*24+j]
        float t[TJ];
#pragma unroll
        for (int q = 0; q < 6; ++q) {
            float4 b = ((const float4*)b1)[jh * 6 + q];
            t[4*q+0] = b.x; t[4*q+1] = b.y; t[4*q+2] = b.z; t[4*q+3] = b.w;
        }
#pragma unroll
        for (int k = 0; k < NE; ++k) {
            const float xk = x[k];
#pragma unroll
            for (int q = 0; q < 6; ++q) {
                float4 w = W[k * 12 + jh * 6 + q];      // wave-uniform -> scalar loads
                t[4*q+0] = fmaf(xk, w.x, t[4*q+0]);
                t[4*q+1] = fmaf(xk, w.y, t[4*q+1]);
                t[4*q+2] = fmaf(xk, w.z, t[4*q+2]);
                t[4*q+3] = fmaf(xk, w.w, t[4*q+3]);
            }
        }

        if (jh == 1) __syncthreads();      // pass-0 reads done before overwrite
        // ---- store transposed: s_t[wid][j][lane]  (bank = (j+lane)%32, 2-way max)
#pragma unroll
        for (int j = 0; j < TJ; ++j) {
            float tv = fmaxf(t[j], 0.0f);
            s_t[wid][j][lane] = valid ? tv : 0.0f;
        }
        __syncthreads();

        // ---- sequential segment reduce + coalesced flush
        if (ract) {
            float sum = 0.0f;
            const float* tp = &s_t[wid][jr][ebase];
            const int*   dp = &s_d[wid][ebase];
#pragma unroll 4
            for (int it = 0; it < 32; ++it) {
                sum += tp[it];
                if ((bhalf >> it) & 1u) {              // uniform within each half
                    int dd = dp[it];                   // broadcast read
                    if (dd >= 0)
                        atomicAdd(tagg + (size_t)dd * NE + jh * TJ + jr, sum);
                    sum = 0.0f;
                }
            }
        }
    }
}

// ---------------- node: W2 GEMV + update MLP (in place on hout) ----------------
__global__ __launch_bounds__(256, 2) void node_kernel(
    const float* __restrict__ hin,
    float* __restrict__ hout,                                      // holds tagg on entry
    const int* __restrict__ cnt,
    const float* __restrict__ w2, const float* __restrict__ b2,    // msg W2 row-major, msg b2
    const float* __restrict__ u1, const float* __restrict__ ub1,   // U1 row-major
    const float* __restrict__ u2, const float* __restrict__ ub2,   // U2 row-major
    int N)
{
    int n = blockIdx.x * 256 + threadIdx.x;
    if (n >= N) return;

    // acc[j] = deg*b2[j] + sum_k tagg[k] * W2[k][j]   (tagg streamed)
    float fdeg = (float)cnt[n];
    float acc[NE];
#pragma unroll
    for (int q = 0; q < 12; ++q) {
        float4 b = ((const float4*)b2)[q];
        acc[4*q+0] = fdeg * b.x; acc[4*q+1] = fdeg * b.y;
        acc[4*q+2] = fdeg * b.z; acc[4*q+3] = fdeg * b.w;
    }
    const float4* tg4 = (const float4*)(hout + (size_t)n * NE);
    const float4* W2 = (const float4*)w2;
    {
        float4 g = tg4[0];
#pragma unroll
        for (int q = 0; q < 12; ++q) {
            float4 gn;
            if (q < 11) gn = tg4[q + 1];
            float g0 = g.x, g1 = g.y, g2 = g.z, g3 = g.w;
#pragma unroll
            for (int kk = 0; kk < 4; ++kk) {
                const float gk = (kk == 0) ? g0 : (kk == 1) ? g1 : (kk == 2) ? g2 : g3;
                const int k = 4 * q + kk;
#pragma unroll
                for (int j = 0; j < 12; ++j) {
                    float4 w = W2[k * 12 + j];
                    acc[4*j+0] = fmaf(gk, w.x, acc[4*j+0]);
                    acc[4*j+1] = fmaf(gk, w.y, acc[4*j+1]);
                    acc[4*j+2] = fmaf(gk, w.z, acc[4*j+2]);
                    acc[4*j+3] = fmaf(gk, w.w, acc[4*j+3]);
                }
            }
            g = gn;
        }
    }

    // t[j] = relu(ub1[j] + sum_k acc[k]*U1[k][j])
    float t[NE];
#pragma unroll
    for (int q = 0; q < 12; ++q) {
        float4 b = ((const float4*)ub1)[q];
        t[4*q+0] = b.x; t[4*q+1] = b.y; t[4*q+2] = b.z; t[4*q+3] = b.w;
    }
    const float4* U1 = (const float4*)u1;
#pragma unroll
    for (int k = 0; k < NE; ++k) {
        const float ak = acc[k];
#pragma unroll
        for (int j = 0; j < 12; ++j) {
            float4 w = U1[k * 12 + j];
            t[4*j+0] = fmaf(ak, w.x, t[4*j+0]);
            t[4*j+1] = fmaf(ak, w.y, t[4*j+1]);
            t[4*j+2] = fmaf(ak, w.z, t[4*j+2]);
            t[4*j+3] = fmaf(ak, w.w, t[4*j+3]);
        }
    }
#pragma unroll
    for (int j = 0; j < NE; ++j) t[j] = fmaxf(t[j], 0.0f);

    // out[j] = hin[j] + ub2[j] + sum_k t[k]*U2[k][j]   (reuse acc as out)
    const float4* hp = (const float4*)(hin + (size_t)n * NE);
#pragma unroll
    for (int q = 0; q < 12; ++q) {
        float4 a = hp[q];
        float4 b = ((const float4*)ub2)[q];
        acc[4*q+0] = a.x + b.x; acc[4*q+1] = a.y + b.y;
        acc[4*q+2] = a.z + b.z; acc[4*q+3] = a.w + b.w;
    }
    const float4* U2 = (const float4*)u2;
#pragma unroll
    for (int k = 0; k < NE; ++k) {
        const float tk = t[k];
#pragma unroll
        for (int j = 0; j < 12; ++j) {
            float4 w = U2[k * 12 + j];
            acc[4*j+0] = fmaf(tk, w.x, acc[4*j+0]);
            acc[4*j+1] = fmaf(tk, w.y, acc[4*j+1]);
            acc[4*j+2] = fmaf(tk, w.z, acc[4*j+2]);
            acc[4*j+3] = fmaf(tk, w.w, acc[4*j+3]);
        }
    }

    float4* ho = (float4*)(hout + (size_t)n * NE);
#pragma unroll
    for (int q = 0; q < 12; ++q)
        ho[q] = make_float4(acc[4*q+0], acc[4*q+1], acc[4*q+2], acc[4*q+3]);
}

// ---------------- readout ----------------
__global__ __launch_bounds__(256, 2) void readout_kernel(const float* __restrict__ h,
                                                         const int* __restrict__ gid,
                                                         const float* __restrict__ w1,  // row-major
                                                         const float* __restrict__ b1,
                                                         const float* __restrict__ w2,  // [48]
                                                         const float* __restrict__ b2,  // [1]
                                                         float* __restrict__ out, int N) {
    int n = blockIdx.x * 256 + threadIdx.x;
    if (n >= N) return;

    float t[NE];
#pragma unroll
    for (int q = 0; q < 12; ++q) {
        float4 b = ((const float4*)b1)[q];
        t[4*q+0] = b.x; t[4*q+1] = b.y; t[4*q+2] = b.z; t[4*q+3] = b.w;
    }
    const float4* hp = (const float4*)(h + (size_t)n * NE);
    const float4* W1 = (const float4*)w1;
    {
        float4 a = hp[0];
#pragma unroll
        for (int q = 0; q < 12; ++q) {
            float4 an;
            if (q < 11) an = hp[q + 1];
            float a0 = a.x, a1 = a.y, a2 = a.z, a3 = a.w;
#pragma unroll
            for (int kk = 0; kk < 4; ++kk) {
                const float xk = (kk == 0) ? a0 : (kk == 1) ? a1 : (kk == 2) ? a2 : a3;
                const int k = 4 * q + kk;
#pragma unroll
                for (int j = 0; j < 12; ++j) {
                    float4 w = W1[k * 12 + j];
                    t[4*j+0] = fmaf(xk, w.x, t[4*j+0]);
                    t[4*j+1] = fmaf(xk, w.y, t[4*j+1]);
                    t[4*j+2] = fmaf(xk, w.z, t[4*j+2]);
                    t[4*j+3] = fmaf(xk, w.w, t[4*j+3]);
                }
            }
            a = an;
        }
    }
    float y = b2[0];
#pragma unroll
    for (int j = 0; j < NE; ++j) y = fmaf(fmaxf(t[j], 0.0f), w2[j], y);
    atomicAdd(out + gid[n], y);
}

extern "C" void kernel_launch(void* const* d_in, const int* in_sizes, int n_in,
                              void* d_out, int out_size, void* d_ws, size_t ws_size,
                              hipStream_t stream) {
    const int*   AtomicNum = (const int*)  d_in[0];
    const int*   Edge      = (const int*)  d_in[1];
    const int*   graph_id  = (const int*)  d_in[2];
    const float* emb       = (const float*)d_in[3];
    const float* msg_w1    = (const float*)d_in[4];
    const float* msg_b1    = (const float*)d_in[5];
    const float* msg_w2    = (const float*)d_in[6];
    const float* msg_b2    = (const float*)d_in[7];
    const float* upd_w1    = (const float*)d_in[8];
    const float* upd_b1    = (const float*)d_in[9];
    const float* upd_w2    = (const float*)d_in[10];
    const float* upd_b2    = (const float*)d_in[11];
    const float* ro_w1     = (const float*)d_in[12];
    const float* ro_b1     = (const float*)d_in[13];
    const float* ro_w2     = (const float*)d_in[14];
    const float* ro_b2     = (const float*)d_in[15];

    const int N = in_sizes[0];          // 100000
    const int E = in_sizes[1] / 2;      // 1600000
    const int* src = Edge;
    const int* dst = Edge + E;

    // workspace layout (~52 MB)
    float* h    = (float*)d_ws;                    // N*48
    float* h2   = h  + (size_t)N * NE;             // N*48
    int*   cnt    = (int*)(h2 + (size_t)N * NE);   // N
    int*   offs   = cnt + N;                       // N
    int2*  pair   = (int2*)(offs + N);             // E (src,dst) sorted by dst

    hipMemsetAsync(d_out, 0, (size_t)out_size * sizeof(float), stream);
    hipMemsetAsync(cnt, 0, (size_t)N * sizeof(int), stream);

    int n4 = N * 12;
    embed_kernel<<<(n4 + 255) / 256, 256, 0, stream>>>(AtomicNum, emb, h, n4);

    hist_kernel<<<(E + 255) / 256, 256, 0, stream>>>(dst, cnt, E);
    scan_kernel<<<1, 1024, 0, stream>>>(cnt, offs, N);
    scatter_kernel<<<(E + 255) / 256, 256, 0, stream>>>(src, dst, offs, pair, E);

    const float* hin = h;
    float* hout = h2;
    for (int l = 0; l < 6; ++l) {
        hipMemsetAsync(hout, 0, (size_t)N * NE * sizeof(float), stream);
        edge_kernel<<<(E + 255) / 256, 256, 0, stream>>>(
            hin, pair, hout,
            msg_w1 + (size_t)l * NE * NE, msg_b1 + (size_t)l * NE,
            E);
        node_kernel<<<(N + 255) / 256, 256, 0, stream>>>(
            hin, hout, cnt,
            msg_w2 + (size_t)l * NE * NE, msg_b2 + (size_t)l * NE,
            upd_w1 + (size_t)l * NE * NE, upd_b1 + (size_t)l * NE,
            upd_w2 + (size_t)l * NE * NE, upd_b2 + (size_t)l * NE,
            N);
        const float* tmp = hin; hin = hout; hout = (float*)tmp;
    }

    readout_kernel<<<(N + 255) / 256, 256, 0, stream>>>(
        hin, graph_id, ro_w1, ro_b1, ro_w2, ro_b2, (float*)d_out, N);
}

// Round 7
// 2173.888 us; speedup vs baseline: 1.9639x; 1.3427x over previous
//
#include <hip/hip_runtime.h>

// VanillaMPNN on MI355X — round 7: MFMA edge GEMM.
// Edge kernel: per wave, 16 edges = one 16x16x32_bf16 M-tile. A-frags built
// in-register from h_src/h_dst gathers (lane m=lane&15 loads its edge's
// k-chunk (lane>>4)*8, K padded 48->64). W1 pre-packed per launch into
// B-fragment tables, hi/lo bf16 split; 3-term MFMA (xh*Wh+xl*Wh+xh*Wl)
// gives ~fp32 accuracy. C-layout puts 4 consecutive edges in one lane's
// 4 acc regs -> segmented reduce = 4 adds + boundary flags, coalesced
// 16-lane atomic flush. No LDS, no scan. Node/readout unchanged (round 6).

#define NE 48

typedef __attribute__((ext_vector_type(8))) short short8;
typedef __attribute__((ext_vector_type(4))) float floatx4;

__device__ __forceinline__ unsigned short bf16_rne(float v) {
    unsigned u = __float_as_uint(v);
    u += 0x7FFFu + ((u >> 16) & 1u);
    return (unsigned short)(u >> 16);
}

// ---------------- embed ----------------
__global__ __launch_bounds__(256) void embed_kernel(const int* __restrict__ an,
                                                    const float* __restrict__ emb,
                                                    float* __restrict__ h, int n4) {
    int i = blockIdx.x * 256 + threadIdx.x;   // over N*12 float4s
    if (i >= n4) return;
    int n = i / 12, q = i - n * 12;
    ((float4*)h)[i] = ((const float4*)emb)[an[n] * 12 + q];
}

// ---------------- CSR build ----------------
__global__ __launch_bounds__(256) void hist_kernel(const int* __restrict__ dst,
                                                   int* __restrict__ cnt, int E) {
    int e = blockIdx.x * 256 + threadIdx.x;
    if (e < E) atomicAdd(&cnt[dst[e]], 1);
}

__global__ __launch_bounds__(1024) void scan_kernel(const int* __restrict__ cnt,
                                                    int* __restrict__ offs, int N) {
    __shared__ int swave[16];
    __shared__ int s_carry;
    const int tid = threadIdx.x;
    const int lane = tid & 63, wid = tid >> 6;
    if (tid == 0) s_carry = 0;
    __syncthreads();
    for (int base = 0; base < N; base += 1024) {
        int i = base + tid;
        int orig = (i < N) ? cnt[i] : 0;
        int v = orig;
#pragma unroll
        for (int off = 1; off < 64; off <<= 1) {
            int u = __shfl_up(v, off, 64);
            if (lane >= off) v += u;
        }
        if (lane == 63) swave[wid] = v;
        __syncthreads();
        if (wid == 0) {
            int w = (lane < 16) ? swave[lane] : 0;
#pragma unroll
            for (int off = 1; off < 16; off <<= 1) {
                int u = __shfl_up(w, off, 64);
                if (lane >= off) w += u;
            }
            if (lane < 16) swave[lane] = w;
        }
        __syncthreads();
        int prefix = (wid > 0) ? swave[wid - 1] : 0;
        int total = swave[15];
        int carry = s_carry;
        if (i < N) offs[i] = carry + prefix + v - orig;   // exclusive scan
        __syncthreads();
        if (tid == 0) s_carry = carry + total;
    }
}

__global__ __launch_bounds__(256) void scatter_kernel(const int* __restrict__ src,
                                                      const int* __restrict__ dst,
                                                      int* __restrict__ offs,
                                                      int2* __restrict__ pair, int E) {
    int e = blockIdx.x * 256 + threadIdx.x;
    if (e < E) {
        int d = dst[e];
        int p = atomicAdd(&offs[d], 1);
        pair[p] = make_int2(src[e], d);   // sorted by d
    }
}

// ---------------- W1 -> B-fragment pack (hi/lo bf16) ----------------
// frag idx = ((l*3 + t)*2 + s)*64 + lane; elem i: k = s*32 + (lane>>4)*8 + i,
// j = t*16 + (lane&15); value = W1[l][k][j] (0 for k>=48).
__global__ __launch_bounds__(256) void pack_w1_kernel(const float* __restrict__ w1,
                                                      short8* __restrict__ hi,
                                                      short8* __restrict__ lo) {
    int idx = blockIdx.x * 256 + threadIdx.x;
    if (idx >= 6 * 3 * 2 * 64) return;
    int lane = idx & 63;
    int s = (idx >> 6) & 1;
    int t = (idx >> 7) % 3;
    int l = (idx >> 7) / 3;
    short8 h8, l8;
#pragma unroll
    for (int i = 0; i < 8; ++i) {
        int k = s * 32 + (lane >> 4) * 8 + i;
        int j = t * 16 + (lane & 15);
        float v = (k < NE) ? w1[l * NE * NE + k * NE + j] : 0.0f;
        unsigned short hh = bf16_rne(v);
        float hf = __uint_as_float((unsigned)hh << 16);
        unsigned short ll = bf16_rne(v - hf);
        h8[i] = (short)hh;
        l8[i] = (short)ll;
    }
    hi[idx] = h8;
    lo[idx] = l8;
}

// ---------------- edge: MFMA GEMM1 + relu + segmented reduce ----------------
__global__ __launch_bounds__(256) void edge_kernel(
    const float* __restrict__ hin,
    const int2* __restrict__ pair,
    float* __restrict__ tagg,                     // == hout, pre-zeroed
    const short8* __restrict__ bhi,               // this layer's [3][2][64]
    const short8* __restrict__ blo,
    const float* __restrict__ b1,
    int E)
{
    const int lane = threadIdx.x & 63;
    const int wid  = threadIdx.x >> 6;
    const int tile = blockIdx.x * 4 + wid;        // 16 edges per wave
    const int e0 = tile * 16;
    if (e0 >= E) return;                          // wave-uniform exit

    const int m  = lane & 15;                     // A row / D col owner
    const int kb = lane >> 4;                     // k-block

    const int e = e0 + m;
    const bool ev = (e < E);
    int2 sd = pair[ev ? e : (E - 1)];
    const int dkey = ev ? sd.y : -1;              // sentinel: never flushed

    const float* hs = hin + (size_t)sd.x * NE + kb * 8;
    const float* hd = hin + (size_t)sd.y * NE + kb * 8;

    // x chunks: step0 k=kb*8..+7 ; step1 k=32+kb*8..+7 (kb<2), else pad 0
    float x0[8], x1[8];
    {
        float4 A0 = ((const float4*)hs)[0];
        float4 A1 = ((const float4*)hs)[1];
        float4 C0 = ((const float4*)hd)[0];
        float4 C1 = ((const float4*)hd)[1];
        x0[0] = A0.x * C0.x; x0[1] = A0.y * C0.y; x0[2] = A0.z * C0.z; x0[3] = A0.w * C0.w;
        x0[4] = A1.x * C1.x; x0[5] = A1.y * C1.y; x0[6] = A1.z * C1.z; x0[7] = A1.w * C1.w;
    }
    if (kb < 2) {
        float4 A0 = ((const float4*)(hs + 32))[0];
        float4 A1 = ((const float4*)(hs + 32))[1];
        float4 C0 = ((const float4*)(hd + 32))[0];
        float4 C1 = ((const float4*)(hd + 32))[1];
        x1[0] = A0.x * C0.x; x1[1] = A0.y * C0.y; x1[2] = A0.z * C0.z; x1[3] = A0.w * C0.w;
        x1[4] = A1.x * C1.x; x1[5] = A1.y * C1.y; x1[6] = A1.z * C1.z; x1[7] = A1.w * C1.w;
    } else {
#pragma unroll
        for (int i = 0; i < 8; ++i) x1[i] = 0.0f;
    }

    // hi/lo bf16 split of A-frags
    short8 ah0, al0, ah1, al1;
#pragma unroll
    for (int i = 0; i < 8; ++i) {
        unsigned short hh = bf16_rne(x0[i]);
        float hf = __uint_as_float((unsigned)hh << 16);
        ah0[i] = (short)hh;
        al0[i] = (short)bf16_rne(x0[i] - hf);
        hh = bf16_rne(x1[i]);
        hf = __uint_as_float((unsigned)hh << 16);
        ah1[i] = (short)hh;
        al1[i] = (short)bf16_rne(x1[i] - hf);
    }

    // 3 j-tiles, 6 MFMA each (3-term split over 2 K-steps)
    floatx4 acc[3];
#pragma unroll
    for (int t = 0; t < 3; ++t) {
        short8 bh0 = bhi[(t * 2 + 0) * 64 + lane];
        short8 bh1 = bhi[(t * 2 + 1) * 64 + lane];
        short8 bl0 = blo[(t * 2 + 0) * 64 + lane];
        short8 bl1 = blo[(t * 2 + 1) * 64 + lane];
        floatx4 c = {0.0f, 0.0f, 0.0f, 0.0f};
        c = __builtin_amdgcn_mfma_f32_16x16x32_bf16(ah0, bh0, c, 0, 0, 0);
        c = __builtin_amdgcn_mfma_f32_16x16x32_bf16(ah1, bh1, c, 0, 0, 0);
        c = __builtin_amdgcn_mfma_f32_16x16x32_bf16(al0, bh0, c, 0, 0, 0);
        c = __builtin_amdgcn_mfma_f32_16x16x32_bf16(al1, bh1, c, 0, 0, 0);
        c = __builtin_amdgcn_mfma_f32_16x16x32_bf16(ah0, bl0, c, 0, 0, 0);
        c = __builtin_amdgcn_mfma_f32_16x16x32_bf16(ah1, bl1, c, 0, 0, 0);
        acc[t] = c;
    }

    // bias + relu.  D layout: row(edge) = kb*4 + r, col(j) = t*16 + m.
    float v0[4], v1[4], v2[4];
    {
        float bb0 = b1[0 * 16 + m], bb1 = b1[1 * 16 + m], bb2 = b1[2 * 16 + m];
#pragma unroll
        for (int r = 0; r < 4; ++r) {
            v0[r] = fmaxf(acc[0][r] + bb0, 0.0f);
            v1[r] = fmaxf(acc[1][r] + bb1, 0.0f);
            v2[r] = fmaxf(acc[2][r] + bb2, 0.0f);
        }
    }
    // (rows of invalid edges produce junk v but their dkey=-1 run is never
    //  flushed, and valid runs flush before the -1 run starts — no mask needed)

    // segmented reduce over the 4 consecutive edges in this lane's regs
    int dd[5];
#pragma unroll
    for (int r = 0; r < 4; ++r) dd[r] = __shfl(dkey, kb * 4 + r, 64);
    dd[4] = -2;                                   // force flush at group end
    float s0 = 0.0f, s1 = 0.0f, s2 = 0.0f;
#pragma unroll
    for (int r = 0; r < 4; ++r) {
        s0 += v0[r]; s1 += v1[r]; s2 += v2[r];
        if (dd[r] != dd[r + 1]) {                 // uniform within 16-lane group
            if (dd[r] >= 0) {
                float* ap = tagg + (size_t)dd[r] * NE + m;
                atomicAdd(ap,      s0);           // 16 lanes -> coalesced
                atomicAdd(ap + 16, s1);
                atomicAdd(ap + 32, s2);
            }
            s0 = 0.0f; s1 = 0.0f; s2 = 0.0f;
        }
    }
}

// ---------------- node: W2 GEMV + update MLP (in place on hout) ----------------
__global__ __launch_bounds__(256, 2) void node_kernel(
    const float* __restrict__ hin,
    float* __restrict__ hout,                                      // holds tagg on entry
    const int* __restrict__ cnt,
    const float* __restrict__ w2, const float* __restrict__ b2,    // msg W2 row-major, msg b2
    const float* __restrict__ u1, const float* __restrict__ ub1,   // U1 row-major
    const float* __restrict__ u2, const float* __restrict__ ub2,   // U2 row-major
    int N)
{
    int n = blockIdx.x * 256 + threadIdx.x;
    if (n >= N) return;

    // acc[j] = deg*b2[j] + sum_k tagg[k] * W2[k][j]   (tagg streamed)
    float fdeg = (float)cnt[n];
    float acc[NE];
#pragma unroll
    for (int q = 0; q < 12; ++q) {
        float4 b = ((const float4*)b2)[q];
        acc[4*q+0] = fdeg * b.x; acc[4*q+1] = fdeg * b.y;
        acc[4*q+2] = fdeg * b.z; acc[4*q+3] = fdeg * b.w;
    }
    const float4* tg4 = (const float4*)(hout + (size_t)n * NE);
    const float4* W2 = (const float4*)w2;
    {
        float4 g = tg4[0];
#pragma unroll
        for (int q = 0; q < 12; ++q) {
            float4 gn;
            if (q < 11) gn = tg4[q + 1];
            float g0 = g.x, g1 = g.y, g2 = g.z, g3 = g.w;
#pragma unroll
            for (int kk = 0; kk < 4; ++kk) {
                const float gk = (kk == 0) ? g0 : (kk == 1) ? g1 : (kk == 2) ? g2 : g3;
                const int k = 4 * q + kk;
#pragma unroll
                for (int j = 0; j < 12; ++j) {
                    float4 w = W2[k * 12 + j];
                    acc[4*j+0] = fmaf(gk, w.x, acc[4*j+0]);
                    acc[4*j+1] = fmaf(gk, w.y, acc[4*j+1]);
                    acc[4*j+2] = fmaf(gk, w.z, acc[4*j+2]);
                    acc[4*j+3] = fmaf(gk, w.w, acc[4*j+3]);
                }
            }
            g = gn;
        }
    }

    // t[j] = relu(ub1[j] + sum_k acc[k]*U1[k][j])
    float t[NE];
#pragma unroll
    for (int q = 0; q < 12; ++q) {
        float4 b = ((const float4*)ub1)[q];
        t[4*q+0] = b.x; t[4*q+1] = b.y; t[4*q+2] = b.z; t[4*q+3] = b.w;
    }
    const float4* U1 = (const float4*)u1;
#pragma unroll
    for (int k = 0; k < NE; ++k) {
        const float ak = acc[k];
#pragma unroll
        for (int j = 0; j < 12; ++j) {
            float4 w = U1[k * 12 + j];
            t[4*j+0] = fmaf(ak, w.x, t[4*j+0]);
            t[4*j+1] = fmaf(ak, w.y, t[4*j+1]);
            t[4*j+2] = fmaf(ak, w.z, t[4*j+2]);
            t[4*j+3] = fmaf(ak, w.w, t[4*j+3]);
        }
    }
#pragma unroll
    for (int j = 0; j < NE; ++j) t[j] = fmaxf(t[j], 0.0f);

    // out[j] = hin[j] + ub2[j] + sum_k t[k]*U2[k][j]   (reuse acc as out)
    const float4* hp = (const float4*)(hin + (size_t)n * NE);
#pragma unroll
    for (int q = 0; q < 12; ++q) {
        float4 a = hp[q];
        float4 b = ((const float4*)ub2)[q];
        acc[4*q+0] = a.x + b.x; acc[4*q+1] = a.y + b.y;
        acc[4*q+2] = a.z + b.z; acc[4*q+3] = a.w + b.w;
    }
    const float4* U2 = (const float4*)u2;
#pragma unroll
    for (int k = 0; k < NE; ++k) {
        const float tk = t[k];
#pragma unroll
        for (int j = 0; j < 12; ++j) {
            float4 w = U2[k * 12 + j];
            acc[4*j+0] = fmaf(tk, w.x, acc[4*j+0]);
            acc[4*j+1] = fmaf(tk, w.y, acc[4*j+1]);
            acc[4*j+2] = fmaf(tk, w.z, acc[4*j+2]);
            acc[4*j+3] = fmaf(tk, w.w, acc[4*j+3]);
        }
    }

    float4* ho = (float4*)(hout + (size_t)n * NE);
#pragma unroll
    for (int q = 0; q < 12; ++q)
        ho[q] = make_float4(acc[4*q+0], acc[4*q+1], acc[4*q+2], acc[4*q+3]);
}

// ---------------- readout ----------------
__global__ __launch_bounds__(256, 2) void readout_kernel(const float* __restrict__ h,
                                                         const int* __restrict__ gid,
                                                         const float* __restrict__ w1,  // row-major
                                                         const float* __restrict__ b1,
                                                         const float* __restrict__ w2,  // [48]
                                                         const float* __restrict__ b2,  // [1]
                                                         float* __restrict__ out, int N) {
    int n = blockIdx.x * 256 + threadIdx.x;
    if (n >= N) return;

    float t[NE];
#pragma unroll
    for (int q = 0; q < 12; ++q) {
        float4 b = ((const float4*)b1)[q];
        t[4*q+0] = b.x; t[4*q+1] = b.y; t[4*q+2] = b.z; t[4*q+3] = b.w;
    }
    const float4* hp = (const float4*)(h + (size_t)n * NE);
    const float4* W1 = (const float4*)w1;
    {
        float4 a = hp[0];
#pragma unroll
        for (int q = 0; q < 12; ++q) {
            float4 an;
            if (q < 11) an = hp[q + 1];
            float a0 = a.x, a1 = a.y, a2 = a.z, a3 = a.w;
#pragma unroll
            for (int kk = 0; kk < 4; ++kk) {
                const float xk = (kk == 0) ? a0 : (kk == 1) ? a1 : (kk == 2) ? a2 : a3;
                const int k = 4 * q + kk;
#pragma unroll
                for (int j = 0; j < 12; ++j) {
                    float4 w = W1[k * 12 + j];
                    t[4*j+0] = fmaf(xk, w.x, t[4*j+0]);
                    t[4*j+1] = fmaf(xk, w.y, t[4*j+1]);
                    t[4*j+2] = fmaf(xk, w.z, t[4*j+2]);
                    t[4*j+3] = fmaf(xk, w.w, t[4*j+3]);
                }
            }
            a = an;
        }
    }
    float y = b2[0];
#pragma unroll
    for (int j = 0; j < NE; ++j) y = fmaf(fmaxf(t[j], 0.0f), w2[j], y);
    atomicAdd(out + gid[n], y);
}

extern "C" void kernel_launch(void* const* d_in, const int* in_sizes, int n_in,
                              void* d_out, int out_size, void* d_ws, size_t ws_size,
                              hipStream_t stream) {
    const int*   AtomicNum = (const int*)  d_in[0];
    const int*   Edge      = (const int*)  d_in[1];
    const int*   graph_id  = (const int*)  d_in[2];
    const float* emb       = (const float*)d_in[3];
    const float* msg_w1    = (const float*)d_in[4];
    const float* msg_b1    = (const float*)d_in[5];
    const float* msg_w2    = (const float*)d_in[6];
    const float* msg_b2    = (const float*)d_in[7];
    const float* upd_w1    = (const float*)d_in[8];
    const float* upd_b1    = (const float*)d_in[9];
    const float* upd_w2    = (const float*)d_in[10];
    const float* upd_b2    = (const float*)d_in[11];
    const float* ro_w1     = (const float*)d_in[12];
    const float* ro_b1     = (const float*)d_in[13];
    const float* ro_w2     = (const float*)d_in[14];
    const float* ro_b2     = (const float*)d_in[15];

    const int N = in_sizes[0];          // 100000
    const int E = in_sizes[1] / 2;      // 1600000
    const int* src = Edge;
    const int* dst = Edge + E;

    // workspace layout (~52.2 MB)
    float*  h    = (float*)d_ws;                       // N*48
    float*  h2   = h  + (size_t)N * NE;                // N*48
    int*    cnt  = (int*)(h2 + (size_t)N * NE);        // N
    int*    offs = cnt + N;                            // N
    int2*   pair = (int2*)(offs + N);                  // E
    short8* whi  = (short8*)(pair + E);                // 6*3*2*64 frags (36 KB)
    short8* wlo  = whi + 6 * 3 * 2 * 64;               // 36 KB

    hipMemsetAsync(d_out, 0, (size_t)out_size * sizeof(float), stream);
    hipMemsetAsync(cnt, 0, (size_t)N * sizeof(int), stream);

    int n4 = N * 12;
    embed_kernel<<<(n4 + 255) / 256, 256, 0, stream>>>(AtomicNum, emb, h, n4);

    hist_kernel<<<(E + 255) / 256, 256, 0, stream>>>(dst, cnt, E);
    scan_kernel<<<1, 1024, 0, stream>>>(cnt, offs, N);
    scatter_kernel<<<(E + 255) / 256, 256, 0, stream>>>(src, dst, offs, pair, E);
    pack_w1_kernel<<<(6 * 3 * 2 * 64 + 255) / 256, 256, 0, stream>>>(msg_w1, whi, wlo);

    const float* hin = h;
    float* hout = h2;
    for (int l = 0; l < 6; ++l) {
        hipMemsetAsync(hout, 0, (size_t)N * NE * sizeof(float), stream);
        edge_kernel<<<(E + 63) / 64, 256, 0, stream>>>(
            hin, pair, hout,
            whi + (size_t)l * 384, wlo + (size_t)l * 384,
            msg_b1 + (size_t)l * NE,
            E);
        node_kernel<<<(N + 255) / 256, 256, 0, stream>>>(
            hin, hout, cnt,
            msg_w2 + (size_t)l * NE * NE, msg_b2 + (size_t)l * NE,
            upd_w1 + (size_t)l * NE * NE, upd_b1 + (size_t)l * NE,
            upd_w2 + (size_t)l * NE * NE, upd_b2 + (size_t)l * NE,
            N);
        const float* tmp = hin; hin = hout; hout = (float*)tmp;
    }

    readout_kernel<<<(N + 255) / 256, 256, 0, stream>>>(
        hin, graph_id, ro_w1, ro_b1, ro_w2, ro_b2, (float*)d_out, N);
}

// Round 8
// 2156.854 us; speedup vs baseline: 1.9794x; 1.0079x over previous
//
#include <hip/hip_runtime.h>

// VanillaMPNN on MI355X — round 8.
// Edge: coalesced row gather (12 lanes per 192B row -> ~3 sector reqs/row,
// 4x fewer L2/IF requests) -> in-register product -> per-wave LDS transpose
// xT[48][17] -> MFMA A-frags via strided b32 reads. MFMA core + segmented
// atomic flush unchanged from round 7 (3-term bf16 split, absmax ~512 ok).
// Node/readout: weights staged in LDS per block (kills scalar-cache thrash
// that stalled the 1.5-wave/SIMD fp32 GEMVs). Math bit-identical fp32.

#define NE 48

typedef __attribute__((ext_vector_type(8))) short short8;
typedef __attribute__((ext_vector_type(4))) float floatx4;

__device__ __forceinline__ unsigned short bf16_rne(float v) {
    unsigned u = __float_as_uint(v);
    u += 0x7FFFu + ((u >> 16) & 1u);
    return (unsigned short)(u >> 16);
}

// ---------------- embed ----------------
__global__ __launch_bounds__(256) void embed_kernel(const int* __restrict__ an,
                                                    const float* __restrict__ emb,
                                                    float* __restrict__ h, int n4) {
    int i = blockIdx.x * 256 + threadIdx.x;   // over N*12 float4s
    if (i >= n4) return;
    int n = i / 12, q = i - n * 12;
    ((float4*)h)[i] = ((const float4*)emb)[an[n] * 12 + q];
}

// ---------------- CSR build ----------------
__global__ __launch_bounds__(256) void hist_kernel(const int* __restrict__ dst,
                                                   int* __restrict__ cnt, int E) {
    int e = blockIdx.x * 256 + threadIdx.x;
    if (e < E) atomicAdd(&cnt[dst[e]], 1);
}

__global__ __launch_bounds__(1024) void scan_kernel(const int* __restrict__ cnt,
                                                    int* __restrict__ offs, int N) {
    __shared__ int swave[16];
    __shared__ int s_carry;
    const int tid = threadIdx.x;
    const int lane = tid & 63, wid = tid >> 6;
    if (tid == 0) s_carry = 0;
    __syncthreads();
    for (int base = 0; base < N; base += 1024) {
        int i = base + tid;
        int orig = (i < N) ? cnt[i] : 0;
        int v = orig;
#pragma unroll
        for (int off = 1; off < 64; off <<= 1) {
            int u = __shfl_up(v, off, 64);
            if (lane >= off) v += u;
        }
        if (lane == 63) swave[wid] = v;
        __syncthreads();
        if (wid == 0) {
            int w = (lane < 16) ? swave[lane] : 0;
#pragma unroll
            for (int off = 1; off < 16; off <<= 1) {
                int u = __shfl_up(w, off, 64);
                if (lane >= off) w += u;
            }
            if (lane < 16) swave[lane] = w;
        }
        __syncthreads();
        int prefix = (wid > 0) ? swave[wid - 1] : 0;
        int total = swave[15];
        int carry = s_carry;
        if (i < N) offs[i] = carry + prefix + v - orig;   // exclusive scan
        __syncthreads();
        if (tid == 0) s_carry = carry + total;
    }
}

__global__ __launch_bounds__(256) void scatter_kernel(const int* __restrict__ src,
                                                      const int* __restrict__ dst,
                                                      int* __restrict__ offs,
                                                      int2* __restrict__ pair, int E) {
    int e = blockIdx.x * 256 + threadIdx.x;
    if (e < E) {
        int d = dst[e];
        int p = atomicAdd(&offs[d], 1);
        pair[p] = make_int2(src[e], d);   // sorted by d
    }
}

// ---------------- W1 -> B-fragment pack (hi/lo bf16) ----------------
__global__ __launch_bounds__(256) void pack_w1_kernel(const float* __restrict__ w1,
                                                      short8* __restrict__ hi,
                                                      short8* __restrict__ lo) {
    int idx = blockIdx.x * 256 + threadIdx.x;
    if (idx >= 6 * 3 * 2 * 64) return;
    int lane = idx & 63;
    int s = (idx >> 6) & 1;
    int t = (idx >> 7) % 3;
    int l = (idx >> 7) / 3;
    short8 h8, l8;
#pragma unroll
    for (int i = 0; i < 8; ++i) {
        int k = s * 32 + (lane >> 4) * 8 + i;
        int j = t * 16 + (lane & 15);
        float v = (k < NE) ? w1[l * NE * NE + k * NE + j] : 0.0f;
        unsigned short hh = bf16_rne(v);
        float hf = __uint_as_float((unsigned)hh << 16);
        unsigned short ll = bf16_rne(v - hf);
        h8[i] = (short)hh;
        l8[i] = (short)ll;
    }
    hi[idx] = h8;
    lo[idx] = l8;
}

// ---------------- edge: coalesced gather + LDS transpose + MFMA ----------------
__global__ __launch_bounds__(256) void edge_kernel(
    const float* __restrict__ hin,
    const int2* __restrict__ pair,
    float* __restrict__ tagg,                     // == hout, pre-zeroed
    const short8* __restrict__ bhi,               // this layer's [3][2][64]
    const short8* __restrict__ blo,
    const float* __restrict__ b1,
    int E)
{
    __shared__ float xT[4][NE][17];               // per-wave [k][edge], stride 17
    const int lane = threadIdx.x & 63;
    const int wid  = threadIdx.x >> 6;
    const int tile = blockIdx.x * 4 + wid;        // 16 edges per wave
    const int e0 = tile * 16;
    if (e0 >= E) return;                          // wave-uniform exit (no block barrier used)

    // ---- coalesced gather: 192 chunks (16 edges x 12 float4), 3 per lane.
    // 12 consecutive lanes cover one contiguous 192B row -> coalesced sectors.
#pragma unroll
    for (int i = 0; i < 3; ++i) {
        int c = lane + 64 * i;                    // 0..191
        int er = c / 12;
        int off = c - er * 12;
        int ee = e0 + er;
        int2 sd2 = pair[(ee < E) ? ee : (E - 1)];
        float4 a = *(const float4*)(hin + (size_t)sd2.x * NE + off * 4);
        float4 b = *(const float4*)(hin + (size_t)sd2.y * NE + off * 4);
        xT[wid][off * 4 + 0][er] = a.x * b.x;
        xT[wid][off * 4 + 1][er] = a.y * b.y;
        xT[wid][off * 4 + 2][er] = a.z * b.z;
        xT[wid][off * 4 + 3][er] = a.w * b.w;
    }
    asm volatile("s_waitcnt lgkmcnt(0)" ::: "memory");   // intra-wave LDS RAW

    const int m  = lane & 15;                     // A row / D col owner
    const int kb = lane >> 4;                     // k-block

    const int e = e0 + m;
    const bool ev = (e < E);
    int dkey;
    { int2 sdm = pair[ev ? e : (E - 1)]; dkey = ev ? sdm.y : -1; }

    // ---- read A chunks from transposed tile (stride 17 -> ~2-way max)
    float x0[8], x1[8];
#pragma unroll
    for (int i = 0; i < 8; ++i) x0[i] = xT[wid][kb * 8 + i][m];
    if (kb < 2) {
#pragma unroll
        for (int i = 0; i < 8; ++i) x1[i] = xT[wid][32 + kb * 8 + i][m];
    } else {
#pragma unroll
        for (int i = 0; i < 8; ++i) x1[i] = 0.0f;
    }

    // hi/lo bf16 split of A-frags
    short8 ah0, al0, ah1, al1;
#pragma unroll
    for (int i = 0; i < 8; ++i) {
        unsigned short hh = bf16_rne(x0[i]);
        float hf = __uint_as_float((unsigned)hh << 16);
        ah0[i] = (short)hh;
        al0[i] = (short)bf16_rne(x0[i] - hf);
        hh = bf16_rne(x1[i]);
        hf = __uint_as_float((unsigned)hh << 16);
        ah1[i] = (short)hh;
        al1[i] = (short)bf16_rne(x1[i] - hf);
    }

    // 3 j-tiles, 6 MFMA each (3-term split over 2 K-steps)
    floatx4 acc[3];
#pragma unroll
    for (int t = 0; t < 3; ++t) {
        short8 bh0 = bhi[(t * 2 + 0) * 64 + lane];
        short8 bh1 = bhi[(t * 2 + 1) * 64 + lane];
        short8 bl0 = blo[(t * 2 + 0) * 64 + lane];
        short8 bl1 = blo[(t * 2 + 1) * 64 + lane];
        floatx4 c = {0.0f, 0.0f, 0.0f, 0.0f};
        c = __builtin_amdgcn_mfma_f32_16x16x32_bf16(ah0, bh0, c, 0, 0, 0);
        c = __builtin_amdgcn_mfma_f32_16x16x32_bf16(ah1, bh1, c, 0, 0, 0);
        c = __builtin_amdgcn_mfma_f32_16x16x32_bf16(al0, bh0, c, 0, 0, 0);
        c = __builtin_amdgcn_mfma_f32_16x16x32_bf16(al1, bh1, c, 0, 0, 0);
        c = __builtin_amdgcn_mfma_f32_16x16x32_bf16(ah0, bl0, c, 0, 0, 0);
        c = __builtin_amdgcn_mfma_f32_16x16x32_bf16(ah1, bl1, c, 0, 0, 0);
        acc[t] = c;
    }

    // bias + relu.  D layout: row(edge) = kb*4 + r, col(j) = t*16 + m.
    float v0[4], v1[4], v2[4];
    {
        float bb0 = b1[0 * 16 + m], bb1 = b1[1 * 16 + m], bb2 = b1[2 * 16 + m];
#pragma unroll
        for (int r = 0; r < 4; ++r) {
            v0[r] = fmaxf(acc[0][r] + bb0, 0.0f);
            v1[r] = fmaxf(acc[1][r] + bb1, 0.0f);
            v2[r] = fmaxf(acc[2][r] + bb2, 0.0f);
        }
    }

    // segmented reduce over the 4 consecutive edges in this lane's regs
    int dd[5];
#pragma unroll
    for (int r = 0; r < 4; ++r) dd[r] = __shfl(dkey, kb * 4 + r, 64);
    dd[4] = -2;                                   // force flush at group end
    float s0 = 0.0f, s1 = 0.0f, s2 = 0.0f;
#pragma unroll
    for (int r = 0; r < 4; ++r) {
        s0 += v0[r]; s1 += v1[r]; s2 += v2[r];
        if (dd[r] != dd[r + 1]) {                 // uniform within 16-lane group
            if (dd[r] >= 0) {
                float* ap = tagg + (size_t)dd[r] * NE + m;
                atomicAdd(ap,      s0);           // 16 lanes -> coalesced
                atomicAdd(ap + 16, s1);
                atomicAdd(ap + 32, s2);
            }
            s0 = 0.0f; s1 = 0.0f; s2 = 0.0f;
        }
    }
}

// ---------------- node: W2 GEMV + update MLP, LDS-staged weights ----------------
__global__ __launch_bounds__(256, 2) void node_kernel(
    const float* __restrict__ hin,
    float* __restrict__ hout,                                      // holds tagg on entry
    const int* __restrict__ cnt,
    const float* __restrict__ w2, const float* __restrict__ b2,    // msg W2 row-major, msg b2
    const float* __restrict__ u1, const float* __restrict__ ub1,   // U1 row-major
    const float* __restrict__ u2, const float* __restrict__ ub2,   // U2 row-major
    int N)
{
    __shared__ __align__(16) float sW2[NE * NE], sU1[NE * NE], sU2[NE * NE];
    __shared__ __align__(16) float sB2[NE], sUB1[NE], sUB2[NE];
    for (int i = threadIdx.x; i < NE * NE / 4; i += 256) {
        ((float4*)sW2)[i] = ((const float4*)w2)[i];
        ((float4*)sU1)[i] = ((const float4*)u1)[i];
        ((float4*)sU2)[i] = ((const float4*)u2)[i];
    }
    if (threadIdx.x < 12)      ((float4*)sB2)[threadIdx.x]       = ((const float4*)b2)[threadIdx.x];
    else if (threadIdx.x < 24) ((float4*)sUB1)[threadIdx.x - 12] = ((const float4*)ub1)[threadIdx.x - 12];
    else if (threadIdx.x < 36) ((float4*)sUB2)[threadIdx.x - 24] = ((const float4*)ub2)[threadIdx.x - 24];
    __syncthreads();

    int n = blockIdx.x * 256 + threadIdx.x;
    if (n >= N) return;

    // acc[j] = deg*b2[j] + sum_k tagg[k] * W2[k][j]   (tagg streamed)
    float fdeg = (float)cnt[n];
    float acc[NE];
#pragma unroll
    for (int q = 0; q < 12; ++q) {
        float4 b = ((const float4*)sB2)[q];
        acc[4*q+0] = fdeg * b.x; acc[4*q+1] = fdeg * b.y;
        acc[4*q+2] = fdeg * b.z; acc[4*q+3] = fdeg * b.w;
    }
    const float4* tg4 = (const float4*)(hout + (size_t)n * NE);
    const float4* W2s = (const float4*)sW2;
    {
        float4 g = tg4[0];
#pragma unroll
        for (int q = 0; q < 12; ++q) {
            float4 gn;
            if (q < 11) gn = tg4[q + 1];
            float g0 = g.x, g1 = g.y, g2 = g.z, g3 = g.w;
#pragma unroll
            for (int kk = 0; kk < 4; ++kk) {
                const float gk = (kk == 0) ? g0 : (kk == 1) ? g1 : (kk == 2) ? g2 : g3;
                const int k = 4 * q + kk;
#pragma unroll
                for (int j = 0; j < 12; ++j) {
                    float4 w = W2s[k * 12 + j];
                    acc[4*j+0] = fmaf(gk, w.x, acc[4*j+0]);
                    acc[4*j+1] = fmaf(gk, w.y, acc[4*j+1]);
                    acc[4*j+2] = fmaf(gk, w.z, acc[4*j+2]);
                    acc[4*j+3] = fmaf(gk, w.w, acc[4*j+3]);
                }
            }
            g = gn;
        }
    }

    // t[j] = relu(ub1[j] + sum_k acc[k]*U1[k][j])
    float t[NE];
#pragma unroll
    for (int q = 0; q < 12; ++q) {
        float4 b = ((const float4*)sUB1)[q];
        t[4*q+0] = b.x; t[4*q+1] = b.y; t[4*q+2] = b.z; t[4*q+3] = b.w;
    }
    const float4* U1s = (const float4*)sU1;
#pragma unroll
    for (int k = 0; k < NE; ++k) {
        const float ak = acc[k];
#pragma unroll
        for (int j = 0; j < 12; ++j) {
            float4 w = U1s[k * 12 + j];
            t[4*j+0] = fmaf(ak, w.x, t[4*j+0]);
            t[4*j+1] = fmaf(ak, w.y, t[4*j+1]);
            t[4*j+2] = fmaf(ak, w.z, t[4*j+2]);
            t[4*j+3] = fmaf(ak, w.w, t[4*j+3]);
        }
    }
#pragma unroll
    for (int j = 0; j < NE; ++j) t[j] = fmaxf(t[j], 0.0f);

    // out[j] = hin[j] + ub2[j] + sum_k t[k]*U2[k][j]   (reuse acc as out)
    const float4* hp = (const float4*)(hin + (size_t)n * NE);
#pragma unroll
    for (int q = 0; q < 12; ++q) {
        float4 a = hp[q];
        float4 b = ((const float4*)sUB2)[q];
        acc[4*q+0] = a.x + b.x; acc[4*q+1] = a.y + b.y;
        acc[4*q+2] = a.z + b.z; acc[4*q+3] = a.w + b.w;
    }
    const float4* U2s = (const float4*)sU2;
#pragma unroll
    for (int k = 0; k < NE; ++k) {
        const float tk = t[k];
#pragma unroll
        for (int j = 0; j < 12; ++j) {
            float4 w = U2s[k * 12 + j];
            acc[4*j+0] = fmaf(tk, w.x, acc[4*j+0]);
            acc[4*j+1] = fmaf(tk, w.y, acc[4*j+1]);
            acc[4*j+2] = fmaf(tk, w.z, acc[4*j+2]);
            acc[4*j+3] = fmaf(tk, w.w, acc[4*j+3]);
        }
    }

    float4* ho = (float4*)(hout + (size_t)n * NE);
#pragma unroll
    for (int q = 0; q < 12; ++q)
        ho[q] = make_float4(acc[4*q+0], acc[4*q+1], acc[4*q+2], acc[4*q+3]);
}

// ---------------- readout (LDS-staged weights) ----------------
__global__ __launch_bounds__(256, 2) void readout_kernel(const float* __restrict__ h,
                                                         const int* __restrict__ gid,
                                                         const float* __restrict__ w1,  // row-major
                                                         const float* __restrict__ b1,
                                                         const float* __restrict__ w2,  // [48]
                                                         const float* __restrict__ b2,  // [1]
                                                         float* __restrict__ out, int N) {
    __shared__ __align__(16) float sW1[NE * NE], sB1[NE], sW2v[NE];
    for (int i = threadIdx.x; i < NE * NE / 4; i += 256)
        ((float4*)sW1)[i] = ((const float4*)w1)[i];
    if (threadIdx.x < 12)      ((float4*)sB1)[threadIdx.x]       = ((const float4*)b1)[threadIdx.x];
    else if (threadIdx.x < 24) ((float4*)sW2v)[threadIdx.x - 12] = ((const float4*)w2)[threadIdx.x - 12];
    __syncthreads();

    int n = blockIdx.x * 256 + threadIdx.x;
    if (n >= N) return;

    float t[NE];
#pragma unroll
    for (int q = 0; q < 12; ++q) {
        float4 b = ((const float4*)sB1)[q];
        t[4*q+0] = b.x; t[4*q+1] = b.y; t[4*q+2] = b.z; t[4*q+3] = b.w;
    }
    const float4* hp = (const float4*)(h + (size_t)n * NE);
    const float4* W1s = (const float4*)sW1;
    {
        float4 a = hp[0];
#pragma unroll
        for (int q = 0; q < 12; ++q) {
            float4 an;
            if (q < 11) an = hp[q + 1];
            float a0 = a.x, a1 = a.y, a2 = a.z, a3 = a.w;
#pragma unroll
            for (int kk = 0; kk < 4; ++kk) {
                const float xk = (kk == 0) ? a0 : (kk == 1) ? a1 : (kk == 2) ? a2 : a3;
                const int k = 4 * q + kk;
#pragma unroll
                for (int j = 0; j < 12; ++j) {
                    float4 w = W1s[k * 12 + j];
                    t[4*j+0] = fmaf(xk, w.x, t[4*j+0]);
                    t[4*j+1] = fmaf(xk, w.y, t[4*j+1]);
                    t[4*j+2] = fmaf(xk, w.z, t[4*j+2]);
                    t[4*j+3] = fmaf(xk, w.w, t[4*j+3]);
                }
            }
            a = an;
        }
    }
    float y = b2[0];
#pragma unroll
    for (int j = 0; j < NE; ++j) y = fmaf(fmaxf(t[j], 0.0f), sW2v[j], y);
    atomicAdd(out + gid[n], y);
}

extern "C" void kernel_launch(void* const* d_in, const int* in_sizes, int n_in,
                              void* d_out, int out_size, void* d_ws, size_t ws_size,
                              hipStream_t stream) {
    const int*   AtomicNum = (const int*)  d_in[0];
    const int*   Edge      = (const int*)  d_in[1];
    const int*   graph_id  = (const int*)  d_in[2];
    const float* emb       = (const float*)d_in[3];
    const float* msg_w1    = (const float*)d_in[4];
    const float* msg_b1    = (const float*)d_in[5];
    const float* msg_w2    = (const float*)d_in[6];
    const float* msg_b2    = (const float*)d_in[7];
    const float* upd_w1    = (const float*)d_in[8];
    const float* upd_b1    = (const float*)d_in[9];
    const float* upd_w2    = (const float*)d_in[10];
    const float* upd_b2    = (const float*)d_in[11];
    const float* ro_w1     = (const float*)d_in[12];
    const float* ro_b1     = (const float*)d_in[13];
    const float* ro_w2     = (const float*)d_in[14];
    const float* ro_b2     = (const float*)d_in[15];

    const int N = in_sizes[0];          // 100000
    const int E = in_sizes[1] / 2;      // 1600000
    const int* src = Edge;
    const int* dst = Edge + E;

    // workspace layout (~52.2 MB)
    float*  h    = (float*)d_ws;                       // N*48
    float*  h2   = h  + (size_t)N * NE;                // N*48
    int*    cnt  = (int*)(h2 + (size_t)N * NE);        // N
    int*    offs = cnt + N;                            // N
    int2*   pair = (int2*)(offs + N);                  // E
    short8* whi  = (short8*)(pair + E);                // 6*3*2*64 frags (36 KB)
    short8* wlo  = whi + 6 * 3 * 2 * 64;               // 36 KB

    hipMemsetAsync(d_out, 0, (size_t)out_size * sizeof(float), stream);
    hipMemsetAsync(cnt, 0, (size_t)N * sizeof(int), stream);

    int n4 = N * 12;
    embed_kernel<<<(n4 + 255) / 256, 256, 0, stream>>>(AtomicNum, emb, h, n4);

    hist_kernel<<<(E + 255) / 256, 256, 0, stream>>>(dst, cnt, E);
    scan_kernel<<<1, 1024, 0, stream>>>(cnt, offs, N);
    scatter_kernel<<<(E + 255) / 256, 256, 0, stream>>>(src, dst, offs, pair, E);
    pack_w1_kernel<<<(6 * 3 * 2 * 64 + 255) / 256, 256, 0, stream>>>(msg_w1, whi, wlo);

    const float* hin = h;
    float* hout = h2;
    for (int l = 0; l < 6; ++l) {
        hipMemsetAsync(hout, 0, (size_t)N * NE * sizeof(float), stream);
        edge_kernel<<<(E + 63) / 64, 256, 0, stream>>>(
            hin, pair, hout,
            whi + (size_t)l * 384, wlo + (size_t)l * 384,
            msg_b1 + (size_t)l * NE,
            E);
        node_kernel<<<(N + 255) / 256, 256, 0, stream>>>(
            hin, hout, cnt,
            msg_w2 + (size_t)l * NE * NE, msg_b2 + (size_t)l * NE,
            upd_w1 + (size_t)l * NE * NE, upd_b1 + (size_t)l * NE,
            upd_w2 + (size_t)l * NE * NE, upd_b2 + (size_t)l * NE,
            N);
        const float* tmp = hin; hin = hout; hout = (float*)tmp;
    }

    readout_kernel<<<(N + 255) / 256, 256, 0, stream>>>(
        hin, graph_id, ro_w1, ro_b1, ro_w2, ro_b2, (float*)d_out, N);
}

// Round 9
// 1610.951 us; speedup vs baseline: 2.6501x; 1.3389x over previous
//
#include <hip/hip_runtime.h>

// VanillaMPNN on MI355X — round 9: node-centric MFMA edge kernel, no atomics.
// One wave = one node: loop its CSR edge list in 16-edge MFMA tiles.
// dst row loaded once (wave-broadcast), src rows gathered per lane, 3-term
// bf16-split MFMA vs pre-packed W1 B-frags (same math as r7/r8, absmax~512).
// Per tile: bias+relu+row-mask, register row-sum accumulation across tiles,
// xor-reduce over kb lanes, one coalesced 192B plain store per node.
// Kills: 131 MB/layer atomic write-through, per-layer hout memset, int2 pair.
// Node/readout unchanged from round 8.

#define NE 48

typedef __attribute__((ext_vector_type(8))) short short8;
typedef __attribute__((ext_vector_type(4))) float floatx4;

__device__ __forceinline__ unsigned short bf16_rne(float v) {
    unsigned u = __float_as_uint(v);
    u += 0x7FFFu + ((u >> 16) & 1u);
    return (unsigned short)(u >> 16);
}

// ---------------- embed ----------------
__global__ __launch_bounds__(256) void embed_kernel(const int* __restrict__ an,
                                                    const float* __restrict__ emb,
                                                    float* __restrict__ h, int n4) {
    int i = blockIdx.x * 256 + threadIdx.x;   // over N*12 float4s
    if (i >= n4) return;
    int n = i / 12, q = i - n * 12;
    ((float4*)h)[i] = ((const float4*)emb)[an[n] * 12 + q];
}

// ---------------- CSR build ----------------
__global__ __launch_bounds__(256) void hist_kernel(const int* __restrict__ dst,
                                                   int* __restrict__ cnt, int E) {
    int e = blockIdx.x * 256 + threadIdx.x;
    if (e < E) atomicAdd(&cnt[dst[e]], 1);
}

__global__ __launch_bounds__(1024) void scan_kernel(const int* __restrict__ cnt,
                                                    int* __restrict__ offs, int N) {
    __shared__ int swave[16];
    __shared__ int s_carry;
    const int tid = threadIdx.x;
    const int lane = tid & 63, wid = tid >> 6;
    if (tid == 0) s_carry = 0;
    __syncthreads();
    for (int base = 0; base < N; base += 1024) {
        int i = base + tid;
        int orig = (i < N) ? cnt[i] : 0;
        int v = orig;
#pragma unroll
        for (int off = 1; off < 64; off <<= 1) {
            int u = __shfl_up(v, off, 64);
            if (lane >= off) v += u;
        }
        if (lane == 63) swave[wid] = v;
        __syncthreads();
        if (wid == 0) {
            int w = (lane < 16) ? swave[lane] : 0;
#pragma unroll
            for (int off = 1; off < 16; off <<= 1) {
                int u = __shfl_up(w, off, 64);
                if (lane >= off) w += u;
            }
            if (lane < 16) swave[lane] = w;
        }
        __syncthreads();
        int prefix = (wid > 0) ? swave[wid - 1] : 0;
        int total = swave[15];
        int carry = s_carry;
        if (i < N) offs[i] = carry + prefix + v - orig;   // exclusive scan
        __syncthreads();
        if (tid == 0) s_carry = carry + total;
    }
}

__global__ __launch_bounds__(256) void scatter_kernel(const int* __restrict__ src,
                                                      const int* __restrict__ dst,
                                                      int* __restrict__ offs,   // becomes END offsets
                                                      int* __restrict__ colsrc, int E) {
    int e = blockIdx.x * 256 + threadIdx.x;
    if (e < E) {
        int p = atomicAdd(&offs[dst[e]], 1);
        colsrc[p] = src[e];
    }
}

// ---------------- W1 -> B-fragment pack (hi/lo bf16) ----------------
__global__ __launch_bounds__(256) void pack_w1_kernel(const float* __restrict__ w1,
                                                      short8* __restrict__ hi,
                                                      short8* __restrict__ lo) {
    int idx = blockIdx.x * 256 + threadIdx.x;
    if (idx >= 6 * 3 * 2 * 64) return;
    int lane = idx & 63;
    int s = (idx >> 6) & 1;
    int t = (idx >> 7) % 3;
    int l = (idx >> 7) / 3;
    short8 h8, l8;
#pragma unroll
    for (int i = 0; i < 8; ++i) {
        int k = s * 32 + (lane >> 4) * 8 + i;
        int j = t * 16 + (lane & 15);
        float v = (k < NE) ? w1[l * NE * NE + k * NE + j] : 0.0f;
        unsigned short hh = bf16_rne(v);
        float hf = __uint_as_float((unsigned)hh << 16);
        unsigned short ll = bf16_rne(v - hf);
        h8[i] = (short)hh;
        l8[i] = (short)ll;
    }
    hi[idx] = h8;
    lo[idx] = l8;
}

// ---------------- edge: node-centric MFMA, plain stores ----------------
__global__ __launch_bounds__(256) void edge_kernel(
    const float* __restrict__ hin,
    const int* __restrict__ colsrc,
    const int* __restrict__ ends,                 // end offsets per node
    const int* __restrict__ cnt,
    float* __restrict__ tagg,                     // == hout, fully overwritten
    const short8* __restrict__ bhi,               // this layer's [3][2][64]
    const short8* __restrict__ blo,
    const float* __restrict__ b1,
    int N)
{
    const int lane = threadIdx.x & 63;
    const int wid  = threadIdx.x >> 6;
    const int n = blockIdx.x * 4 + wid;           // one wave = one node
    if (n >= N) return;                           // wave-uniform exit

    const int m  = lane & 15;                     // edge-in-tile owner (A) / j-col (D)
    const int kb = lane >> 4;                     // k-block

    const int deg = cnt[n];                       // wave-uniform
    const int end = ends[n];
    const int beg = end - deg;

    // dst row chunks — same node for all edges: wave-broadcast loads
    const float* hd = hin + (size_t)n * NE;
    float4 d0a = ((const float4*)(hd + kb * 8))[0];
    float4 d0b = ((const float4*)(hd + kb * 8))[1];
    float4 d1a = make_float4(0, 0, 0, 0), d1b = d1a;
    if (kb < 2) {
        d1a = ((const float4*)(hd + 32 + kb * 8))[0];
        d1b = ((const float4*)(hd + 32 + kb * 8))[1];
    }

    // B-frags (register-resident across all tiles)
    short8 bh[6], bl[6];
#pragma unroll
    for (int i = 0; i < 6; ++i) { bh[i] = bhi[i * 64 + lane]; bl[i] = blo[i * 64 + lane]; }

    const float bb0 = b1[m], bb1 = b1[16 + m], bb2 = b1[32 + m];

    float s0 = 0.0f, s1 = 0.0f, s2 = 0.0f;       // per-lane partial col sums
    const int ntile = (deg + 15) >> 4;

    for (int it = 0; it < ntile; ++it) {
        const int rem = deg - it * 16;            // valid rows this tile
        int eidx = beg + it * 16 + m;
        int srow = colsrc[(m < rem) ? eidx : beg];
        const float* hs = hin + (size_t)srow * NE + kb * 8;

        float x0[8], x1[8];
        {
            float4 a0 = ((const float4*)hs)[0];
            float4 a1 = ((const float4*)hs)[1];
            x0[0] = a0.x * d0a.x; x0[1] = a0.y * d0a.y; x0[2] = a0.z * d0a.z; x0[3] = a0.w * d0a.w;
            x0[4] = a1.x * d0b.x; x0[5] = a1.y * d0b.y; x0[6] = a1.z * d0b.z; x0[7] = a1.w * d0b.w;
        }
        if (kb < 2) {
            float4 a0 = ((const float4*)(hs + 32))[0];
            float4 a1 = ((const float4*)(hs + 32))[1];
            x1[0] = a0.x * d1a.x; x1[1] = a0.y * d1a.y; x1[2] = a0.z * d1a.z; x1[3] = a0.w * d1a.w;
            x1[4] = a1.x * d1b.x; x1[5] = a1.y * d1b.y; x1[6] = a1.z * d1b.z; x1[7] = a1.w * d1b.w;
        } else {
#pragma unroll
            for (int i = 0; i < 8; ++i) x1[i] = 0.0f;
        }

        // hi/lo bf16 split of A-frags
        short8 ah0, al0, ah1, al1;
#pragma unroll
        for (int i = 0; i < 8; ++i) {
            unsigned short hh = bf16_rne(x0[i]);
            float hf = __uint_as_float((unsigned)hh << 16);
            ah0[i] = (short)hh;
            al0[i] = (short)bf16_rne(x0[i] - hf);
            hh = bf16_rne(x1[i]);
            hf = __uint_as_float((unsigned)hh << 16);
            ah1[i] = (short)hh;
            al1[i] = (short)bf16_rne(x1[i] - hf);
        }

        // 3 j-tiles, 6 MFMA each (3-term split over 2 K-steps), C=0 per tile
#pragma unroll
        for (int t = 0; t < 3; ++t) {
            short8 bh0 = bh[t * 2 + 0], bh1 = bh[t * 2 + 1];
            short8 bl0 = bl[t * 2 + 0], bl1 = bl[t * 2 + 1];
            floatx4 c = {0.0f, 0.0f, 0.0f, 0.0f};
            c = __builtin_amdgcn_mfma_f32_16x16x32_bf16(ah0, bh0, c, 0, 0, 0);
            c = __builtin_amdgcn_mfma_f32_16x16x32_bf16(ah1, bh1, c, 0, 0, 0);
            c = __builtin_amdgcn_mfma_f32_16x16x32_bf16(al0, bh0, c, 0, 0, 0);
            c = __builtin_amdgcn_mfma_f32_16x16x32_bf16(al1, bh1, c, 0, 0, 0);
            c = __builtin_amdgcn_mfma_f32_16x16x32_bf16(ah0, bl0, c, 0, 0, 0);
            c = __builtin_amdgcn_mfma_f32_16x16x32_bf16(ah1, bl1, c, 0, 0, 0);
            // bias + relu + row-mask, accumulate row-sum (rows = edges kb*4+r)
            const float bb = (t == 0) ? bb0 : (t == 1) ? bb1 : bb2;
            float ts = 0.0f;
#pragma unroll
            for (int r = 0; r < 4; ++r) {
                float v = fmaxf(c[r] + bb, 0.0f);
                v = (kb * 4 + r < rem) ? v : 0.0f;
                ts += v;
            }
            if (t == 0) s0 += ts; else if (t == 1) s1 += ts; else s2 += ts;
        }
    }

    // reduce over kb groups (lanes m, m+16, m+32, m+48)
    s0 += __shfl_xor(s0, 16, 64); s0 += __shfl_xor(s0, 32, 64);
    s1 += __shfl_xor(s1, 16, 64); s1 += __shfl_xor(s1, 32, 64);
    s2 += __shfl_xor(s2, 16, 64); s2 += __shfl_xor(s2, 32, 64);

    // pack to one coalesced 192B store: lane L<48 stores col L
    float t1 = __shfl(s1, lane & 15, 64);
    float t2 = __shfl(s2, lane & 15, 64);
    float val = (lane < 16) ? s0 : (lane < 32) ? t1 : t2;
    if (lane < 48) tagg[(size_t)n * NE + lane] = val;
}

// ---------------- node: W2 GEMV + update MLP, LDS-staged weights ----------------
__global__ __launch_bounds__(256, 2) void node_kernel(
    const float* __restrict__ hin,
    float* __restrict__ hout,                                      // holds tagg on entry
    const int* __restrict__ cnt,
    const float* __restrict__ w2, const float* __restrict__ b2,    // msg W2 row-major, msg b2
    const float* __restrict__ u1, const float* __restrict__ ub1,   // U1 row-major
    const float* __restrict__ u2, const float* __restrict__ ub2,   // U2 row-major
    int N)
{
    __shared__ __align__(16) float sW2[NE * NE], sU1[NE * NE], sU2[NE * NE];
    __shared__ __align__(16) float sB2[NE], sUB1[NE], sUB2[NE];
    for (int i = threadIdx.x; i < NE * NE / 4; i += 256) {
        ((float4*)sW2)[i] = ((const float4*)w2)[i];
        ((float4*)sU1)[i] = ((const float4*)u1)[i];
        ((float4*)sU2)[i] = ((const float4*)u2)[i];
    }
    if (threadIdx.x < 12)      ((float4*)sB2)[threadIdx.x]       = ((const float4*)b2)[threadIdx.x];
    else if (threadIdx.x < 24) ((float4*)sUB1)[threadIdx.x - 12] = ((const float4*)ub1)[threadIdx.x - 12];
    else if (threadIdx.x < 36) ((float4*)sUB2)[threadIdx.x - 24] = ((const float4*)ub2)[threadIdx.x - 24];
    __syncthreads();

    int n = blockIdx.x * 256 + threadIdx.x;
    if (n >= N) return;

    // acc[j] = deg*b2[j] + sum_k tagg[k] * W2[k][j]   (tagg streamed)
    float fdeg = (float)cnt[n];
    float acc[NE];
#pragma unroll
    for (int q = 0; q < 12; ++q) {
        float4 b = ((const float4*)sB2)[q];
        acc[4*q+0] = fdeg * b.x; acc[4*q+1] = fdeg * b.y;
        acc[4*q+2] = fdeg * b.z; acc[4*q+3] = fdeg * b.w;
    }
    const float4* tg4 = (const float4*)(hout + (size_t)n * NE);
    const float4* W2s = (const float4*)sW2;
    {
        float4 g = tg4[0];
#pragma unroll
        for (int q = 0; q < 12; ++q) {
            float4 gn;
            if (q < 11) gn = tg4[q + 1];
            float g0 = g.x, g1 = g.y, g2 = g.z, g3 = g.w;
#pragma unroll
            for (int kk = 0; kk < 4; ++kk) {
                const float gk = (kk == 0) ? g0 : (kk == 1) ? g1 : (kk == 2) ? g2 : g3;
                const int k = 4 * q + kk;
#pragma unroll
                for (int j = 0; j < 12; ++j) {
                    float4 w = W2s[k * 12 + j];
                    acc[4*j+0] = fmaf(gk, w.x, acc[4*j+0]);
                    acc[4*j+1] = fmaf(gk, w.y, acc[4*j+1]);
                    acc[4*j+2] = fmaf(gk, w.z, acc[4*j+2]);
                    acc[4*j+3] = fmaf(gk, w.w, acc[4*j+3]);
                }
            }
            g = gn;
        }
    }

    // t[j] = relu(ub1[j] + sum_k acc[k]*U1[k][j])
    float t[NE];
#pragma unroll
    for (int q = 0; q < 12; ++q) {
        float4 b = ((const float4*)sUB1)[q];
        t[4*q+0] = b.x; t[4*q+1] = b.y; t[4*q+2] = b.z; t[4*q+3] = b.w;
    }
    const float4* U1s = (const float4*)sU1;
#pragma unroll
    for (int k = 0; k < NE; ++k) {
        const float ak = acc[k];
#pragma unroll
        for (int j = 0; j < 12; ++j) {
            float4 w = U1s[k * 12 + j];
            t[4*j+0] = fmaf(ak, w.x, t[4*j+0]);
            t[4*j+1] = fmaf(ak, w.y, t[4*j+1]);
            t[4*j+2] = fmaf(ak, w.z, t[4*j+2]);
            t[4*j+3] = fmaf(ak, w.w, t[4*j+3]);
        }
    }
#pragma unroll
    for (int j = 0; j < NE; ++j) t[j] = fmaxf(t[j], 0.0f);

    // out[j] = hin[j] + ub2[j] + sum_k t[k]*U2[k][j]   (reuse acc as out)
    const float4* hp = (const float4*)(hin + (size_t)n * NE);
#pragma unroll
    for (int q = 0; q < 12; ++q) {
        float4 a = hp[q];
        float4 b = ((const float4*)sUB2)[q];
        acc[4*q+0] = a.x + b.x; acc[4*q+1] = a.y + b.y;
        acc[4*q+2] = a.z + b.z; acc[4*q+3] = a.w + b.w;
    }
    const float4* U2s = (const float4*)sU2;
#pragma unroll
    for (int k = 0; k < NE; ++k) {
        const float tk = t[k];
#pragma unroll
        for (int j = 0; j < 12; ++j) {
            float4 w = U2s[k * 12 + j];
            acc[4*j+0] = fmaf(tk, w.x, acc[4*j+0]);
            acc[4*j+1] = fmaf(tk, w.y, acc[4*j+1]);
            acc[4*j+2] = fmaf(tk, w.z, acc[4*j+2]);
            acc[4*j+3] = fmaf(tk, w.w, acc[4*j+3]);
        }
    }

    float4* ho = (float4*)(hout + (size_t)n * NE);
#pragma unroll
    for (int q = 0; q < 12; ++q)
        ho[q] = make_float4(acc[4*q+0], acc[4*q+1], acc[4*q+2], acc[4*q+3]);
}

// ---------------- readout (LDS-staged weights) ----------------
__global__ __launch_bounds__(256, 2) void readout_kernel(const float* __restrict__ h,
                                                         const int* __restrict__ gid,
                                                         const float* __restrict__ w1,  // row-major
                                                         const float* __restrict__ b1,
                                                         const float* __restrict__ w2,  // [48]
                                                         const float* __restrict__ b2,  // [1]
                                                         float* __restrict__ out, int N) {
    __shared__ __align__(16) float sW1[NE * NE], sB1[NE], sW2v[NE];
    for (int i = threadIdx.x; i < NE * NE / 4; i += 256)
        ((float4*)sW1)[i] = ((const float4*)w1)[i];
    if (threadIdx.x < 12)      ((float4*)sB1)[threadIdx.x]       = ((const float4*)b1)[threadIdx.x];
    else if (threadIdx.x < 24) ((float4*)sW2v)[threadIdx.x - 12] = ((const float4*)w2)[threadIdx.x - 12];
    __syncthreads();

    int n = blockIdx.x * 256 + threadIdx.x;
    if (n >= N) return;

    float t[NE];
#pragma unroll
    for (int q = 0; q < 12; ++q) {
        float4 b = ((const float4*)sB1)[q];
        t[4*q+0] = b.x; t[4*q+1] = b.y; t[4*q+2] = b.z; t[4*q+3] = b.w;
    }
    const float4* hp = (const float4*)(h + (size_t)n * NE);
    const float4* W1s = (const float4*)sW1;
    {
        float4 a = hp[0];
#pragma unroll
        for (int q = 0; q < 12; ++q) {
            float4 an;
            if (q < 11) an = hp[q + 1];
            float a0 = a.x, a1 = a.y, a2 = a.z, a3 = a.w;
#pragma unroll
            for (int kk = 0; kk < 4; ++kk) {
                const float xk = (kk == 0) ? a0 : (kk == 1) ? a1 : (kk == 2) ? a2 : a3;
                const int k = 4 * q + kk;
#pragma unroll
                for (int j = 0; j < 12; ++j) {
                    float4 w = W1s[k * 12 + j];
                    t[4*j+0] = fmaf(xk, w.x, t[4*j+0]);
                    t[4*j+1] = fmaf(xk, w.y, t[4*j+1]);
                    t[4*j+2] = fmaf(xk, w.z, t[4*j+2]);
                    t[4*j+3] = fmaf(xk, w.w, t[4*j+3]);
                }
            }
            a = an;
        }
    }
    float y = b2[0];
#pragma unroll
    for (int j = 0; j < NE; ++j) y = fmaf(fmaxf(t[j], 0.0f), sW2v[j], y);
    atomicAdd(out + gid[n], y);
}

extern "C" void kernel_launch(void* const* d_in, const int* in_sizes, int n_in,
                              void* d_out, int out_size, void* d_ws, size_t ws_size,
                              hipStream_t stream) {
    const int*   AtomicNum = (const int*)  d_in[0];
    const int*   Edge      = (const int*)  d_in[1];
    const int*   graph_id  = (const int*)  d_in[2];
    const float* emb       = (const float*)d_in[3];
    const float* msg_w1    = (const float*)d_in[4];
    const float* msg_b1    = (const float*)d_in[5];
    const float* msg_w2    = (const float*)d_in[6];
    const float* msg_b2    = (const float*)d_in[7];
    const float* upd_w1    = (const float*)d_in[8];
    const float* upd_b1    = (const float*)d_in[9];
    const float* upd_w2    = (const float*)d_in[10];
    const float* upd_b2    = (const float*)d_in[11];
    const float* ro_w1     = (const float*)d_in[12];
    const float* ro_b1     = (const float*)d_in[13];
    const float* ro_w2     = (const float*)d_in[14];
    const float* ro_b2     = (const float*)d_in[15];

    const int N = in_sizes[0];          // 100000
    const int E = in_sizes[1] / 2;      // 1600000
    const int* src = Edge;
    const int* dst = Edge + E;

    // workspace layout (~46 MB)
    float*  h    = (float*)d_ws;                       // N*48
    float*  h2   = h  + (size_t)N * NE;                // N*48
    int*    cnt  = (int*)(h2 + (size_t)N * NE);        // N
    int*    offs = cnt + N;                            // N (end offsets after scatter)
    int*    colsrc = offs + N;                         // E
    short8* whi  = (short8*)(colsrc + E);              // 6*3*2*64 frags (36 KB)
    short8* wlo  = whi + 6 * 3 * 2 * 64;               // 36 KB

    hipMemsetAsync(d_out, 0, (size_t)out_size * sizeof(float), stream);
    hipMemsetAsync(cnt, 0, (size_t)N * sizeof(int), stream);

    int n4 = N * 12;
    embed_kernel<<<(n4 + 255) / 256, 256, 0, stream>>>(AtomicNum, emb, h, n4);

    hist_kernel<<<(E + 255) / 256, 256, 0, stream>>>(dst, cnt, E);
    scan_kernel<<<1, 1024, 0, stream>>>(cnt, offs, N);
    scatter_kernel<<<(E + 255) / 256, 256, 0, stream>>>(src, dst, offs, colsrc, E);
    pack_w1_kernel<<<(6 * 3 * 2 * 64 + 255) / 256, 256, 0, stream>>>(msg_w1, whi, wlo);

    const float* hin = h;
    float* hout = h2;
    for (int l = 0; l < 6; ++l) {
        edge_kernel<<<(N + 3) / 4, 256, 0, stream>>>(
            hin, colsrc, offs, cnt, hout,
            whi + (size_t)l * 384, wlo + (size_t)l * 384,
            msg_b1 + (size_t)l * NE,
            N);
        node_kernel<<<(N + 255) / 256, 256, 0, stream>>>(
            hin, hout, cnt,
            msg_w2 + (size_t)l * NE * NE, msg_b2 + (size_t)l * NE,
            upd_w1 + (size_t)l * NE * NE, upd_b1 + (size_t)l * NE,
            upd_w2 + (size_t)l * NE * NE, upd_b2 + (size_t)l * NE,
            N);
        const float* tmp = hin; hin = hout; hout = (float*)tmp;
    }

    readout_kernel<<<(N + 255) / 256, 256, 0, stream>>>(
        hin, graph_id, ro_w1, ro_b1, ro_w2, ro_b2, (float*)d_out, N);
}

// Round 10
// 1347.056 us; speedup vs baseline: 3.1693x; 1.1959x over previous
//
#include <hip/hip_runtime.h>

// VanillaMPNN on MI355X — round 10: MFMA node kernel.
// Edge kernel unchanged from round 9 (node-centric MFMA, no atomics).
// Node kernel: one wave = 16 consecutive nodes; 3 chained 16x48 GEMMs
// (tagg@W2+deg*b2 -> relu(@U1+ub1) -> @U2 + hin + ub2) via 3-term bf16-split
// MFMA with pre-packed B-frags (W2/U1/U2, pack kernel reused). C->A layout
// transform between GEMMs via per-wave LDS tile [16][52] (intra-wave
// lgkmcnt sync only). Replaces ~20k LDS-broadcast cycles/wave (old fp32
// GEMV node kernel was LDS-pipe-bound) with ~54 MFMA + ~36 LDS ops.

#define NE 48

typedef __attribute__((ext_vector_type(8))) short short8;
typedef __attribute__((ext_vector_type(4))) float floatx4;

__device__ __forceinline__ unsigned short bf16_rne(float v) {
    unsigned u = __float_as_uint(v);
    u += 0x7FFFu + ((u >> 16) & 1u);
    return (unsigned short)(u >> 16);
}

__device__ __forceinline__ void split8(const float* x, short8& hi, short8& lo) {
#pragma unroll
    for (int i = 0; i < 8; ++i) {
        unsigned short hh = bf16_rne(x[i]);
        float hf = __uint_as_float((unsigned)hh << 16);
        hi[i] = (short)hh;
        lo[i] = (short)bf16_rne(x[i] - hf);
    }
}

// 3 j-tiles, 6 MFMA each: acc[t] = split3(A) @ B[t]
__device__ __forceinline__ void gemm3(const short8& ah0, const short8& al0,
                                      const short8& ah1, const short8& al1,
                                      const short8* __restrict__ hi,
                                      const short8* __restrict__ lo,
                                      int lane, floatx4* acc) {
#pragma unroll
    for (int t = 0; t < 3; ++t) {
        short8 bh0 = hi[(t * 2 + 0) * 64 + lane];
        short8 bh1 = hi[(t * 2 + 1) * 64 + lane];
        short8 bl0 = lo[(t * 2 + 0) * 64 + lane];
        short8 bl1 = lo[(t * 2 + 1) * 64 + lane];
        floatx4 c = {0.0f, 0.0f, 0.0f, 0.0f};
        c = __builtin_amdgcn_mfma_f32_16x16x32_bf16(ah0, bh0, c, 0, 0, 0);
        c = __builtin_amdgcn_mfma_f32_16x16x32_bf16(ah1, bh1, c, 0, 0, 0);
        c = __builtin_amdgcn_mfma_f32_16x16x32_bf16(al0, bh0, c, 0, 0, 0);
        c = __builtin_amdgcn_mfma_f32_16x16x32_bf16(al1, bh1, c, 0, 0, 0);
        c = __builtin_amdgcn_mfma_f32_16x16x32_bf16(ah0, bl0, c, 0, 0, 0);
        c = __builtin_amdgcn_mfma_f32_16x16x32_bf16(ah1, bl1, c, 0, 0, 0);
        acc[t] = c;
    }
}

// ---------------- embed ----------------
__global__ __launch_bounds__(256) void embed_kernel(const int* __restrict__ an,
                                                    const float* __restrict__ emb,
                                                    float* __restrict__ h, int n4) {
    int i = blockIdx.x * 256 + threadIdx.x;   // over N*12 float4s
    if (i >= n4) return;
    int n = i / 12, q = i - n * 12;
    ((float4*)h)[i] = ((const float4*)emb)[an[n] * 12 + q];
}

// ---------------- CSR build ----------------
__global__ __launch_bounds__(256) void hist_kernel(const int* __restrict__ dst,
                                                   int* __restrict__ cnt, int E) {
    int e = blockIdx.x * 256 + threadIdx.x;
    if (e < E) atomicAdd(&cnt[dst[e]], 1);
}

__global__ __launch_bounds__(1024) void scan_kernel(const int* __restrict__ cnt,
                                                    int* __restrict__ offs, int N) {
    __shared__ int swave[16];
    __shared__ int s_carry;
    const int tid = threadIdx.x;
    const int lane = tid & 63, wid = tid >> 6;
    if (tid == 0) s_carry = 0;
    __syncthreads();
    for (int base = 0; base < N; base += 1024) {
        int i = base + tid;
        int orig = (i < N) ? cnt[i] : 0;
        int v = orig;
#pragma unroll
        for (int off = 1; off < 64; off <<= 1) {
            int u = __shfl_up(v, off, 64);
            if (lane >= off) v += u;
        }
        if (lane == 63) swave[wid] = v;
        __syncthreads();
        if (wid == 0) {
            int w = (lane < 16) ? swave[lane] : 0;
#pragma unroll
            for (int off = 1; off < 16; off <<= 1) {
                int u = __shfl_up(w, off, 64);
                if (lane >= off) w += u;
            }
            if (lane < 16) swave[lane] = w;
        }
        __syncthreads();
        int prefix = (wid > 0) ? swave[wid - 1] : 0;
        int total = swave[15];
        int carry = s_carry;
        if (i < N) offs[i] = carry + prefix + v - orig;   // exclusive scan
        __syncthreads();
        if (tid == 0) s_carry = carry + total;
    }
}

__global__ __launch_bounds__(256) void scatter_kernel(const int* __restrict__ src,
                                                      const int* __restrict__ dst,
                                                      int* __restrict__ offs,   // becomes END offsets
                                                      int* __restrict__ colsrc, int E) {
    int e = blockIdx.x * 256 + threadIdx.x;
    if (e < E) {
        int p = atomicAdd(&offs[dst[e]], 1);
        colsrc[p] = src[e];
    }
}

// ---------------- W (6 layers, 48x48 row-major) -> B-fragment pack ----------------
__global__ __launch_bounds__(256) void pack_w_kernel(const float* __restrict__ w,
                                                     short8* __restrict__ hi,
                                                     short8* __restrict__ lo) {
    int idx = blockIdx.x * 256 + threadIdx.x;
    if (idx >= 6 * 3 * 2 * 64) return;
    int lane = idx & 63;
    int s = (idx >> 6) & 1;
    int t = (idx >> 7) % 3;
    int l = (idx >> 7) / 3;
    short8 h8, l8;
#pragma unroll
    for (int i = 0; i < 8; ++i) {
        int k = s * 32 + (lane >> 4) * 8 + i;
        int j = t * 16 + (lane & 15);
        float v = (k < NE) ? w[l * NE * NE + k * NE + j] : 0.0f;
        unsigned short hh = bf16_rne(v);
        float hf = __uint_as_float((unsigned)hh << 16);
        unsigned short ll = bf16_rne(v - hf);
        h8[i] = (short)hh;
        l8[i] = (short)ll;
    }
    hi[idx] = h8;
    lo[idx] = l8;
}

// ---------------- edge: node-centric MFMA, plain stores (round 9) ----------------
__global__ __launch_bounds__(256) void edge_kernel(
    const float* __restrict__ hin,
    const int* __restrict__ colsrc,
    const int* __restrict__ ends,                 // end offsets per node
    const int* __restrict__ cnt,
    float* __restrict__ tagg,                     // == hout, fully overwritten
    const short8* __restrict__ bhi,               // this layer's [3][2][64]
    const short8* __restrict__ blo,
    const float* __restrict__ b1,
    int N)
{
    const int lane = threadIdx.x & 63;
    const int wid  = threadIdx.x >> 6;
    const int n = blockIdx.x * 4 + wid;           // one wave = one node
    if (n >= N) return;                           // wave-uniform exit

    const int m  = lane & 15;                     // edge-in-tile owner (A) / j-col (D)
    const int kb = lane >> 4;                     // k-block

    const int deg = cnt[n];                       // wave-uniform
    const int end = ends[n];
    const int beg = end - deg;

    // dst row chunks — same node for all edges: wave-broadcast loads
    const float* hd = hin + (size_t)n * NE;
    float4 d0a = ((const float4*)(hd + kb * 8))[0];
    float4 d0b = ((const float4*)(hd + kb * 8))[1];
    float4 d1a = make_float4(0, 0, 0, 0), d1b = d1a;
    if (kb < 2) {
        d1a = ((const float4*)(hd + 32 + kb * 8))[0];
        d1b = ((const float4*)(hd + 32 + kb * 8))[1];
    }

    // B-frags (register-resident across all tiles)
    short8 bh[6], bl[6];
#pragma unroll
    for (int i = 0; i < 6; ++i) { bh[i] = bhi[i * 64 + lane]; bl[i] = blo[i * 64 + lane]; }

    const float bb0 = b1[m], bb1 = b1[16 + m], bb2 = b1[32 + m];

    float s0 = 0.0f, s1 = 0.0f, s2 = 0.0f;       // per-lane partial col sums
    const int ntile = (deg + 15) >> 4;

    for (int it = 0; it < ntile; ++it) {
        const int rem = deg - it * 16;            // valid rows this tile
        int eidx = beg + it * 16 + m;
        int srow = colsrc[(m < rem) ? eidx : beg];
        const float* hs = hin + (size_t)srow * NE + kb * 8;

        float x0[8], x1[8];
        {
            float4 a0 = ((const float4*)hs)[0];
            float4 a1 = ((const float4*)hs)[1];
            x0[0] = a0.x * d0a.x; x0[1] = a0.y * d0a.y; x0[2] = a0.z * d0a.z; x0[3] = a0.w * d0a.w;
            x0[4] = a1.x * d0b.x; x0[5] = a1.y * d0b.y; x0[6] = a1.z * d0b.z; x0[7] = a1.w * d0b.w;
        }
        if (kb < 2) {
            float4 a0 = ((const float4*)(hs + 32))[0];
            float4 a1 = ((const float4*)(hs + 32))[1];
            x1[0] = a0.x * d1a.x; x1[1] = a0.y * d1a.y; x1[2] = a0.z * d1a.z; x1[3] = a0.w * d1a.w;
            x1[4] = a1.x * d1b.x; x1[5] = a1.y * d1b.y; x1[6] = a1.z * d1b.z; x1[7] = a1.w * d1b.w;
        } else {
#pragma unroll
            for (int i = 0; i < 8; ++i) x1[i] = 0.0f;
        }

        short8 ah0, al0, ah1, al1;
        split8(x0, ah0, al0);
        split8(x1, ah1, al1);

        // 3 j-tiles, 6 MFMA each (3-term split over 2 K-steps), C=0 per tile
#pragma unroll
        for (int t = 0; t < 3; ++t) {
            short8 bh0 = bh[t * 2 + 0], bh1 = bh[t * 2 + 1];
            short8 bl0 = bl[t * 2 + 0], bl1 = bl[t * 2 + 1];
            floatx4 c = {0.0f, 0.0f, 0.0f, 0.0f};
            c = __builtin_amdgcn_mfma_f32_16x16x32_bf16(ah0, bh0, c, 0, 0, 0);
            c = __builtin_amdgcn_mfma_f32_16x16x32_bf16(ah1, bh1, c, 0, 0, 0);
            c = __builtin_amdgcn_mfma_f32_16x16x32_bf16(al0, bh0, c, 0, 0, 0);
            c = __builtin_amdgcn_mfma_f32_16x16x32_bf16(al1, bh1, c, 0, 0, 0);
            c = __builtin_amdgcn_mfma_f32_16x16x32_bf16(ah0, bl0, c, 0, 0, 0);
            c = __builtin_amdgcn_mfma_f32_16x16x32_bf16(ah1, bl1, c, 0, 0, 0);
            // bias + relu + row-mask, accumulate row-sum (rows = edges kb*4+r)
            const float bb = (t == 0) ? bb0 : (t == 1) ? bb1 : bb2;
            float ts = 0.0f;
#pragma unroll
            for (int r = 0; r < 4; ++r) {
                float v = fmaxf(c[r] + bb, 0.0f);
                v = (kb * 4 + r < rem) ? v : 0.0f;
                ts += v;
            }
            if (t == 0) s0 += ts; else if (t == 1) s1 += ts; else s2 += ts;
        }
    }

    // reduce over kb groups (lanes m, m+16, m+32, m+48)
    s0 += __shfl_xor(s0, 16, 64); s0 += __shfl_xor(s0, 32, 64);
    s1 += __shfl_xor(s1, 16, 64); s1 += __shfl_xor(s1, 32, 64);
    s2 += __shfl_xor(s2, 16, 64); s2 += __shfl_xor(s2, 32, 64);

    // pack to one coalesced 192B store: lane L<48 stores col L
    float t1 = __shfl(s1, lane & 15, 64);
    float t2 = __shfl(s2, lane & 15, 64);
    float val = (lane < 16) ? s0 : (lane < 32) ? t1 : t2;
    if (lane < 48) tagg[(size_t)n * NE + lane] = val;
}

// ---------------- node: 3 chained MFMA GEMMs over 16 nodes/wave ----------------
__global__ __launch_bounds__(256) void node_kernel(
    const float* __restrict__ hin,
    float* __restrict__ hout,                     // holds tagg on entry
    const int* __restrict__ cnt,
    const short8* __restrict__ w2hi, const short8* __restrict__ w2lo, const float* __restrict__ b2,
    const short8* __restrict__ u1hi, const short8* __restrict__ u1lo, const float* __restrict__ ub1,
    const short8* __restrict__ u2hi, const short8* __restrict__ u2lo, const float* __restrict__ ub2,
    int N)
{
    __shared__ float tile[4][16][52];             // per-wave C->A transpose tile
    const int lane = threadIdx.x & 63;
    const int wid  = threadIdx.x >> 6;
    const int n0 = (blockIdx.x * 4 + wid) * 16;
    if (n0 >= N) return;                          // wave-uniform (N % 16 == 0)

    const int m  = lane & 15;
    const int kb = lane >> 4;

    // ---- A-frags from tagg rows n0..n0+15 (contiguous -> coalesced)
    float c0[8], c1[8];
    {
        const float* tg = hout + (size_t)(n0 + m) * NE;
        *(float4*)(c0)     = *(const float4*)(tg + kb * 8);
        *(float4*)(c0 + 4) = *(const float4*)(tg + kb * 8 + 4);
        if (kb < 2) {
            *(float4*)(c1)     = *(const float4*)(tg + 32 + kb * 8);
            *(float4*)(c1 + 4) = *(const float4*)(tg + 32 + kb * 8 + 4);
        } else {
#pragma unroll
            for (int i = 0; i < 8; ++i) c1[i] = 0.0f;
        }
    }
    short8 ah0, al0, ah1, al1;
    split8(c0, ah0, al0);
    split8(c1, ah1, al1);

    floatx4 acc[3];
    gemm3(ah0, al0, ah1, al1, w2hi, w2lo, lane, acc);   // tagg @ W2

    // + deg * b2   (C layout: row = n0+kb*4+r, col j = t*16+m)
    {
        float b2j[3];
#pragma unroll
        for (int t = 0; t < 3; ++t) b2j[t] = b2[t * 16 + m];
#pragma unroll
        for (int r = 0; r < 4; ++r) {
            float fd = (float)cnt[n0 + kb * 4 + r];
#pragma unroll
            for (int t = 0; t < 3; ++t) acc[t][r] = fmaf(fd, b2j[t], acc[t][r]);
        }
    }

    // ---- transpose C->A (agg), GEMM2: relu(agg @ U1 + ub1)
#pragma unroll
    for (int t = 0; t < 3; ++t)
#pragma unroll
        for (int r = 0; r < 4; ++r)
            tile[wid][kb * 4 + r][t * 16 + m] = acc[t][r];
    asm volatile("s_waitcnt lgkmcnt(0)" ::: "memory");
    {
        const float* row = &tile[wid][m][0];
        *(float4*)(c0)     = *(const float4*)(row + kb * 8);
        *(float4*)(c0 + 4) = *(const float4*)(row + kb * 8 + 4);
        if (kb < 2) {
            *(float4*)(c1)     = *(const float4*)(row + 32 + kb * 8);
            *(float4*)(c1 + 4) = *(const float4*)(row + 32 + kb * 8 + 4);
        } else {
#pragma unroll
            for (int i = 0; i < 8; ++i) c1[i] = 0.0f;
        }
    }
    asm volatile("s_waitcnt lgkmcnt(0)" ::: "memory");   // reads done before overwrite
    split8(c0, ah0, al0);
    split8(c1, ah1, al1);
    gemm3(ah0, al0, ah1, al1, u1hi, u1lo, lane, acc);
    {
        float bj[3];
#pragma unroll
        for (int t = 0; t < 3; ++t) bj[t] = ub1[t * 16 + m];
#pragma unroll
        for (int t = 0; t < 3; ++t)
#pragma unroll
            for (int r = 0; r < 4; ++r)
                acc[t][r] = fmaxf(acc[t][r] + bj[t], 0.0f);
    }

    // ---- transpose C->A (t), GEMM3: t @ U2
#pragma unroll
    for (int t = 0; t < 3; ++t)
#pragma unroll
        for (int r = 0; r < 4; ++r)
            tile[wid][kb * 4 + r][t * 16 + m] = acc[t][r];
    asm volatile("s_waitcnt lgkmcnt(0)" ::: "memory");
    {
        const float* row = &tile[wid][m][0];
        *(float4*)(c0)     = *(const float4*)(row + kb * 8);
        *(float4*)(c0 + 4) = *(const float4*)(row + kb * 8 + 4);
        if (kb < 2) {
            *(float4*)(c1)     = *(const float4*)(row + 32 + kb * 8);
            *(float4*)(c1 + 4) = *(const float4*)(row + 32 + kb * 8 + 4);
        } else {
#pragma unroll
            for (int i = 0; i < 8; ++i) c1[i] = 0.0f;
        }
    }
    split8(c0, ah0, al0);
    split8(c1, ah1, al1);
    gemm3(ah0, al0, ah1, al1, u2hi, u2lo, lane, acc);

    // ---- out = hin + ub2 + acc ; store (coalesced 64B groups per (r,t))
    {
        float bj[3];
#pragma unroll
        for (int t = 0; t < 3; ++t) bj[t] = ub2[t * 16 + m];
#pragma unroll
        for (int r = 0; r < 4; ++r) {
            const size_t row = (size_t)(n0 + kb * 4 + r) * NE;
#pragma unroll
            for (int t = 0; t < 3; ++t) {
                int j = t * 16 + m;
                hout[row + j] = hin[row + j] + bj[t] + acc[t][r];
            }
        }
    }
}

// ---------------- readout (LDS-staged weights) ----------------
__global__ __launch_bounds__(256, 2) void readout_kernel(const float* __restrict__ h,
                                                         const int* __restrict__ gid,
                                                         const float* __restrict__ w1,  // row-major
                                                         const float* __restrict__ b1,
                                                         const float* __restrict__ w2,  // [48]
                                                         const float* __restrict__ b2,  // [1]
                                                         float* __restrict__ out, int N) {
    __shared__ __align__(16) float sW1[NE * NE], sB1[NE], sW2v[NE];
    for (int i = threadIdx.x; i < NE * NE / 4; i += 256)
        ((float4*)sW1)[i] = ((const float4*)w1)[i];
    if (threadIdx.x < 12)      ((float4*)sB1)[threadIdx.x]       = ((const float4*)b1)[threadIdx.x];
    else if (threadIdx.x < 24) ((float4*)sW2v)[threadIdx.x - 12] = ((const float4*)w2)[threadIdx.x - 12];
    __syncthreads();

    int n = blockIdx.x * 256 + threadIdx.x;
    if (n >= N) return;

    float t[NE];
#pragma unroll
    for (int q = 0; q < 12; ++q) {
        float4 b = ((const float4*)sB1)[q];
        t[4*q+0] = b.x; t[4*q+1] = b.y; t[4*q+2] = b.z; t[4*q+3] = b.w;
    }
    const float4* hp = (const float4*)(h + (size_t)n * NE);
    const float4* W1s = (const float4*)sW1;
    {
        float4 a = hp[0];
#pragma unroll
        for (int q = 0; q < 12; ++q) {
            float4 an;
            if (q < 11) an = hp[q + 1];
            float a0 = a.x, a1 = a.y, a2 = a.z, a3 = a.w;
#pragma unroll
            for (int kk = 0; kk < 4; ++kk) {
                const float xk = (kk == 0) ? a0 : (kk == 1) ? a1 : (kk == 2) ? a2 : a3;
                const int k = 4 * q + kk;
#pragma unroll
                for (int j = 0; j < 12; ++j) {
                    float4 w = W1s[k * 12 + j];
                    t[4*j+0] = fmaf(xk, w.x, t[4*j+0]);
                    t[4*j+1] = fmaf(xk, w.y, t[4*j+1]);
                    t[4*j+2] = fmaf(xk, w.z, t[4*j+2]);
                    t[4*j+3] = fmaf(xk, w.w, t[4*j+3]);
                }
            }
            a = an;
        }
    }
    float y = b2[0];
#pragma unroll
    for (int j = 0; j < NE; ++j) y = fmaf(fmaxf(t[j], 0.0f), sW2v[j], y);
    atomicAdd(out + gid[n], y);
}

extern "C" void kernel_launch(void* const* d_in, const int* in_sizes, int n_in,
                              void* d_out, int out_size, void* d_ws, size_t ws_size,
                              hipStream_t stream) {
    const int*   AtomicNum = (const int*)  d_in[0];
    const int*   Edge      = (const int*)  d_in[1];
    const int*   graph_id  = (const int*)  d_in[2];
    const float* emb       = (const float*)d_in[3];
    const float* msg_w1    = (const float*)d_in[4];
    const float* msg_b1    = (const float*)d_in[5];
    const float* msg_w2    = (const float*)d_in[6];
    const float* msg_b2    = (const float*)d_in[7];
    const float* upd_w1    = (const float*)d_in[8];
    const float* upd_b1    = (const float*)d_in[9];
    const float* upd_w2    = (const float*)d_in[10];
    const float* upd_b2    = (const float*)d_in[11];
    const float* ro_w1     = (const float*)d_in[12];
    const float* ro_b1     = (const float*)d_in[13];
    const float* ro_w2     = (const float*)d_in[14];
    const float* ro_b2     = (const float*)d_in[15];

    const int N = in_sizes[0];          // 100000 (divisible by 16)
    const int E = in_sizes[1] / 2;      // 1600000
    const int* src = Edge;
    const int* dst = Edge + E;

    // workspace layout (~46 MB)
    float*  h    = (float*)d_ws;                       // N*48
    float*  h2   = h  + (size_t)N * NE;                // N*48
    int*    cnt  = (int*)(h2 + (size_t)N * NE);        // N
    int*    offs = cnt + N;                            // N (end offsets after scatter)
    int*    colsrc = offs + N;                         // E
    // 4 packed matrices (msg_w1, msg_w2, upd_w1, upd_w2), each 6*384 short8
    short8* whi  = (short8*)(colsrc + E);              // 4*2304
    short8* wlo  = whi + 4 * 2304;                     // 4*2304

    hipMemsetAsync(d_out, 0, (size_t)out_size * sizeof(float), stream);
    hipMemsetAsync(cnt, 0, (size_t)N * sizeof(int), stream);

    int n4 = N * 12;
    embed_kernel<<<(n4 + 255) / 256, 256, 0, stream>>>(AtomicNum, emb, h, n4);

    hist_kernel<<<(E + 255) / 256, 256, 0, stream>>>(dst, cnt, E);
    scan_kernel<<<1, 1024, 0, stream>>>(cnt, offs, N);
    scatter_kernel<<<(E + 255) / 256, 256, 0, stream>>>(src, dst, offs, colsrc, E);

    const int PK = 6 * 3 * 2 * 64;   // 2304
    pack_w_kernel<<<(PK + 255) / 256, 256, 0, stream>>>(msg_w1, whi + 0 * 2304, wlo + 0 * 2304);
    pack_w_kernel<<<(PK + 255) / 256, 256, 0, stream>>>(msg_w2, whi + 1 * 2304, wlo + 1 * 2304);
    pack_w_kernel<<<(PK + 255) / 256, 256, 0, stream>>>(upd_w1, whi + 2 * 2304, wlo + 2 * 2304);
    pack_w_kernel<<<(PK + 255) / 256, 256, 0, stream>>>(upd_w2, whi + 3 * 2304, wlo + 3 * 2304);

    const float* hin = h;
    float* hout = h2;
    for (int l = 0; l < 6; ++l) {
        edge_kernel<<<(N + 3) / 4, 256, 0, stream>>>(
            hin, colsrc, offs, cnt, hout,
            whi + 0 * 2304 + (size_t)l * 384, wlo + 0 * 2304 + (size_t)l * 384,
            msg_b1 + (size_t)l * NE,
            N);
        node_kernel<<<(N / 16 + 3) / 4, 256, 0, stream>>>(
            hin, hout, cnt,
            whi + 1 * 2304 + (size_t)l * 384, wlo + 1 * 2304 + (size_t)l * 384, msg_b2 + (size_t)l * NE,
            whi + 2 * 2304 + (size_t)l * 384, wlo + 2 * 2304 + (size_t)l * 384, upd_b1 + (size_t)l * NE,
            whi + 3 * 2304 + (size_t)l * 384, wlo + 3 * 2304 + (size_t)l * 384, upd_b2 + (size_t)l * NE,
            N);
        const float* tmp = hin; hin = hout; hout = (float*)tmp;
    }

    readout_kernel<<<(N + 255) / 256, 256, 0, stream>>>(
        hin, graph_id, ro_w1, ro_b1, ro_w2, ro_b2, (float*)d_out, N);
}

// Round 11
// 1039.192 us; speedup vs baseline: 4.1082x; 1.2963x over previous
//
#include <hip/hip_runtime.h>
#include <hip/hip_bf16.h>

// VanillaMPNN on MI355X — round 11: cheaper splits + 4-node edge waves.
// Edge kernel (node-centric MFMA, no atomics, round 9/10 structure) with:
//  (1) packed bf16 hi/lo split via __float22bfloat162_rn (v_cvt_pk_bf16_f32):
//      ~3 VALU/elem vs ~10 scalar — the split was ~2x the MFMA time.
//  (2) one wave = 4 consecutive nodes: amortizes B-frag/bias setup over
//      ~5.9 tiles (vs 1.47) and gives 4 independent streams to hide the
//      scattered h_src gather latency.
// Node kernel: same 3-chained-GEMM MFMA as round 10, packed splits.

#define NE 48

typedef __attribute__((ext_vector_type(8))) short short8;
typedef __attribute__((ext_vector_type(4))) float floatx4;

__device__ __forceinline__ unsigned short bf16_rne(float v) {
    unsigned u = __float_as_uint(v);
    u += 0x7FFFu + ((u >> 16) & 1u);
    return (unsigned short)(u >> 16);
}

// packed hi/lo split: 8 fp32 -> 8 bf16 hi + 8 bf16 lo (RNE both)
__device__ __forceinline__ void split8p(const float* __restrict__ x, short8& hi, short8& lo) {
    union { unsigned u[4]; short8 s; } H, L;
#pragma unroll
    for (int i = 0; i < 4; ++i) {
        float a = x[2 * i], b = x[2 * i + 1];
        __hip_bfloat162 h2 = __float22bfloat162_rn(make_float2(a, b));
        unsigned h = *reinterpret_cast<unsigned*>(&h2);      // elem0 low16, elem1 high16
        float ra = a - __uint_as_float(h << 16);
        float rb = b - __uint_as_float(h & 0xFFFF0000u);
        __hip_bfloat162 l2 = __float22bfloat162_rn(make_float2(ra, rb));
        H.u[i] = h;
        L.u[i] = *reinterpret_cast<unsigned*>(&l2);
    }
    hi = H.s; lo = L.s;
}

// 3 j-tiles, 6 MFMA each: acc[t] = split3(A) @ B[t]
__device__ __forceinline__ void gemm3(const short8& ah0, const short8& al0,
                                      const short8& ah1, const short8& al1,
                                      const short8* __restrict__ hi,
                                      const short8* __restrict__ lo,
                                      int lane, floatx4* acc) {
#pragma unroll
    for (int t = 0; t < 3; ++t) {
        short8 bh0 = hi[(t * 2 + 0) * 64 + lane];
        short8 bh1 = hi[(t * 2 + 1) * 64 + lane];
        short8 bl0 = lo[(t * 2 + 0) * 64 + lane];
        short8 bl1 = lo[(t * 2 + 1) * 64 + lane];
        floatx4 c = {0.0f, 0.0f, 0.0f, 0.0f};
        c = __builtin_amdgcn_mfma_f32_16x16x32_bf16(ah0, bh0, c, 0, 0, 0);
        c = __builtin_amdgcn_mfma_f32_16x16x32_bf16(ah1, bh1, c, 0, 0, 0);
        c = __builtin_amdgcn_mfma_f32_16x16x32_bf16(al0, bh0, c, 0, 0, 0);
        c = __builtin_amdgcn_mfma_f32_16x16x32_bf16(al1, bh1, c, 0, 0, 0);
        c = __builtin_amdgcn_mfma_f32_16x16x32_bf16(ah0, bl0, c, 0, 0, 0);
        c = __builtin_amdgcn_mfma_f32_16x16x32_bf16(ah1, bl1, c, 0, 0, 0);
        acc[t] = c;
    }
}

// ---------------- embed ----------------
__global__ __launch_bounds__(256) void embed_kernel(const int* __restrict__ an,
                                                    const float* __restrict__ emb,
                                                    float* __restrict__ h, int n4) {
    int i = blockIdx.x * 256 + threadIdx.x;   // over N*12 float4s
    if (i >= n4) return;
    int n = i / 12, q = i - n * 12;
    ((float4*)h)[i] = ((const float4*)emb)[an[n] * 12 + q];
}

// ---------------- CSR build ----------------
__global__ __launch_bounds__(256) void hist_kernel(const int* __restrict__ dst,
                                                   int* __restrict__ cnt, int E) {
    int e = blockIdx.x * 256 + threadIdx.x;
    if (e < E) atomicAdd(&cnt[dst[e]], 1);
}

__global__ __launch_bounds__(1024) void scan_kernel(const int* __restrict__ cnt,
                                                    int* __restrict__ offs, int N) {
    __shared__ int swave[16];
    __shared__ int s_carry;
    const int tid = threadIdx.x;
    const int lane = tid & 63, wid = tid >> 6;
    if (tid == 0) s_carry = 0;
    __syncthreads();
    for (int base = 0; base < N; base += 1024) {
        int i = base + tid;
        int orig = (i < N) ? cnt[i] : 0;
        int v = orig;
#pragma unroll
        for (int off = 1; off < 64; off <<= 1) {
            int u = __shfl_up(v, off, 64);
            if (lane >= off) v += u;
        }
        if (lane == 63) swave[wid] = v;
        __syncthreads();
        if (wid == 0) {
            int w = (lane < 16) ? swave[lane] : 0;
#pragma unroll
            for (int off = 1; off < 16; off <<= 1) {
                int u = __shfl_up(w, off, 64);
                if (lane >= off) w += u;
            }
            if (lane < 16) swave[lane] = w;
        }
        __syncthreads();
        int prefix = (wid > 0) ? swave[wid - 1] : 0;
        int total = swave[15];
        int carry = s_carry;
        if (i < N) offs[i] = carry + prefix + v - orig;   // exclusive scan
        __syncthreads();
        if (tid == 0) s_carry = carry + total;
    }
}

__global__ __launch_bounds__(256) void scatter_kernel(const int* __restrict__ src,
                                                      const int* __restrict__ dst,
                                                      int* __restrict__ offs,   // becomes END offsets
                                                      int* __restrict__ colsrc, int E) {
    int e = blockIdx.x * 256 + threadIdx.x;
    if (e < E) {
        int p = atomicAdd(&offs[dst[e]], 1);
        colsrc[p] = src[e];
    }
}

// ---------------- W (6 layers, 48x48 row-major) -> B-fragment pack ----------------
__global__ __launch_bounds__(256) void pack_w_kernel(const float* __restrict__ w,
                                                     short8* __restrict__ hi,
                                                     short8* __restrict__ lo) {
    int idx = blockIdx.x * 256 + threadIdx.x;
    if (idx >= 6 * 3 * 2 * 64) return;
    int lane = idx & 63;
    int s = (idx >> 6) & 1;
    int t = (idx >> 7) % 3;
    int l = (idx >> 7) / 3;
    short8 h8, l8;
#pragma unroll
    for (int i = 0; i < 8; ++i) {
        int k = s * 32 + (lane >> 4) * 8 + i;
        int j = t * 16 + (lane & 15);
        float v = (k < NE) ? w[l * NE * NE + k * NE + j] : 0.0f;
        unsigned short hh = bf16_rne(v);
        float hf = __uint_as_float((unsigned)hh << 16);
        unsigned short ll = bf16_rne(v - hf);
        h8[i] = (short)hh;
        l8[i] = (short)ll;
    }
    hi[idx] = h8;
    lo[idx] = l8;
}

// ---------------- edge: node-centric MFMA, 4 nodes/wave ----------------
__global__ __launch_bounds__(256) void edge_kernel(
    const float* __restrict__ hin,
    const int* __restrict__ colsrc,
    const int* __restrict__ ends,                 // end offsets per node
    const int* __restrict__ cnt,
    float* __restrict__ tagg,                     // == hout, fully overwritten
    const short8* __restrict__ bhi,               // this layer's [3][2][64]
    const short8* __restrict__ blo,
    const float* __restrict__ b1,
    int N)
{
    const int lane = threadIdx.x & 63;
    const int wid  = threadIdx.x >> 6;
    const int n0 = (blockIdx.x * 4 + wid) * 4;    // 4 consecutive nodes per wave
    if (n0 >= N) return;                          // wave-uniform exit (N % 4 == 0)

    const int m  = lane & 15;                     // edge-in-tile owner (A) / j-col (D)
    const int kb = lane >> 4;                     // k-block

    // B-frags + biases: loaded once per wave, amortized over ~5.9 tiles
    short8 bh[6], bl[6];
#pragma unroll
    for (int i = 0; i < 6; ++i) { bh[i] = bhi[i * 64 + lane]; bl[i] = blo[i * 64 + lane]; }
    const float bb0 = b1[m], bb1 = b1[16 + m], bb2 = b1[32 + m];

#pragma unroll 1
    for (int nn = 0; nn < 4; ++nn) {
        const int n = n0 + nn;
        const int deg = cnt[n];                   // wave-uniform
        const int end = ends[n];
        const int beg = end - deg;

        // dst row chunks — same node for all edges: wave-broadcast loads
        const float* hd = hin + (size_t)n * NE;
        float4 d0a = ((const float4*)(hd + kb * 8))[0];
        float4 d0b = ((const float4*)(hd + kb * 8))[1];
        float4 d1a = make_float4(0, 0, 0, 0), d1b = d1a;
        if (kb < 2) {
            d1a = ((const float4*)(hd + 32 + kb * 8))[0];
            d1b = ((const float4*)(hd + 32 + kb * 8))[1];
        }

        float s0 = 0.0f, s1 = 0.0f, s2 = 0.0f;    // per-lane partial col sums
        const int ntile = (deg + 15) >> 4;

        for (int it = 0; it < ntile; ++it) {
            const int rem = deg - it * 16;        // valid rows this tile
            int eidx = beg + it * 16 + m;
            int srow = colsrc[(m < rem) ? eidx : beg];
            const float* hs = hin + (size_t)srow * NE + kb * 8;

            float x0[8], x1[8];
            {
                float4 a0 = ((const float4*)hs)[0];
                float4 a1 = ((const float4*)hs)[1];
                x0[0] = a0.x * d0a.x; x0[1] = a0.y * d0a.y; x0[2] = a0.z * d0a.z; x0[3] = a0.w * d0a.w;
                x0[4] = a1.x * d0b.x; x0[5] = a1.y * d0b.y; x0[6] = a1.z * d0b.z; x0[7] = a1.w * d0b.w;
            }
            if (kb < 2) {
                float4 a0 = ((const float4*)(hs + 32))[0];
                float4 a1 = ((const float4*)(hs + 32))[1];
                x1[0] = a0.x * d1a.x; x1[1] = a0.y * d1a.y; x1[2] = a0.z * d1a.z; x1[3] = a0.w * d1a.w;
                x1[4] = a1.x * d1b.x; x1[5] = a1.y * d1b.y; x1[6] = a1.z * d1b.z; x1[7] = a1.w * d1b.w;
            } else {
#pragma unroll
                for (int i = 0; i < 8; ++i) x1[i] = 0.0f;
            }

            short8 ah0, al0, ah1, al1;
            split8p(x0, ah0, al0);
            split8p(x1, ah1, al1);

            // 3 j-tiles, 6 MFMA each (3-term split over 2 K-steps), C=0 per tile
#pragma unroll
            for (int t = 0; t < 3; ++t) {
                short8 bh0 = bh[t * 2 + 0], bh1 = bh[t * 2 + 1];
                short8 bl0 = bl[t * 2 + 0], bl1 = bl[t * 2 + 1];
                floatx4 c = {0.0f, 0.0f, 0.0f, 0.0f};
                c = __builtin_amdgcn_mfma_f32_16x16x32_bf16(ah0, bh0, c, 0, 0, 0);
                c = __builtin_amdgcn_mfma_f32_16x16x32_bf16(ah1, bh1, c, 0, 0, 0);
                c = __builtin_amdgcn_mfma_f32_16x16x32_bf16(al0, bh0, c, 0, 0, 0);
                c = __builtin_amdgcn_mfma_f32_16x16x32_bf16(al1, bh1, c, 0, 0, 0);
                c = __builtin_amdgcn_mfma_f32_16x16x32_bf16(ah0, bl0, c, 0, 0, 0);
                c = __builtin_amdgcn_mfma_f32_16x16x32_bf16(ah1, bl1, c, 0, 0, 0);
                // bias + relu + row-mask, accumulate row-sum (rows = edges kb*4+r)
                const float bb = (t == 0) ? bb0 : (t == 1) ? bb1 : bb2;
                float ts = 0.0f;
#pragma unroll
                for (int r = 0; r < 4; ++r) {
                    float v = fmaxf(c[r] + bb, 0.0f);
                    v = (kb * 4 + r < rem) ? v : 0.0f;
                    ts += v;
                }
                if (t == 0) s0 += ts; else if (t == 1) s1 += ts; else s2 += ts;
            }
        }

        // reduce over kb groups (lanes m, m+16, m+32, m+48)
        s0 += __shfl_xor(s0, 16, 64); s0 += __shfl_xor(s0, 32, 64);
        s1 += __shfl_xor(s1, 16, 64); s1 += __shfl_xor(s1, 32, 64);
        s2 += __shfl_xor(s2, 16, 64); s2 += __shfl_xor(s2, 32, 64);

        // pack to one coalesced 192B store: lane L<48 stores col L
        float t1 = __shfl(s1, lane & 15, 64);
        float t2 = __shfl(s2, lane & 15, 64);
        float val = (lane < 16) ? s0 : (lane < 32) ? t1 : t2;
        if (lane < 48) tagg[(size_t)n * NE + lane] = val;
    }
}

// ---------------- node: 3 chained MFMA GEMMs over 16 nodes/wave ----------------
__global__ __launch_bounds__(256) void node_kernel(
    const float* __restrict__ hin,
    float* __restrict__ hout,                     // holds tagg on entry
    const int* __restrict__ cnt,
    const short8* __restrict__ w2hi, const short8* __restrict__ w2lo, const float* __restrict__ b2,
    const short8* __restrict__ u1hi, const short8* __restrict__ u1lo, const float* __restrict__ ub1,
    const short8* __restrict__ u2hi, const short8* __restrict__ u2lo, const float* __restrict__ ub2,
    int N)
{
    __shared__ float tile[4][16][52];             // per-wave C->A transpose tile
    const int lane = threadIdx.x & 63;
    const int wid  = threadIdx.x >> 6;
    const int n0 = (blockIdx.x * 4 + wid) * 16;
    if (n0 >= N) return;                          // wave-uniform (N % 16 == 0)

    const int m  = lane & 15;
    const int kb = lane >> 4;

    // ---- A-frags from tagg rows n0..n0+15 (contiguous -> coalesced)
    float c0[8], c1[8];
    {
        const float* tg = hout + (size_t)(n0 + m) * NE;
        *(float4*)(c0)     = *(const float4*)(tg + kb * 8);
        *(float4*)(c0 + 4) = *(const float4*)(tg + kb * 8 + 4);
        if (kb < 2) {
            *(float4*)(c1)     = *(const float4*)(tg + 32 + kb * 8);
            *(float4*)(c1 + 4) = *(const float4*)(tg + 32 + kb * 8 + 4);
        } else {
#pragma unroll
            for (int i = 0; i < 8; ++i) c1[i] = 0.0f;
        }
    }
    short8 ah0, al0, ah1, al1;
    split8p(c0, ah0, al0);
    split8p(c1, ah1, al1);

    floatx4 acc[3];
    gemm3(ah0, al0, ah1, al1, w2hi, w2lo, lane, acc);   // tagg @ W2

    // + deg * b2   (C layout: row = n0+kb*4+r, col j = t*16+m)
    {
        float b2j[3];
#pragma unroll
        for (int t = 0; t < 3; ++t) b2j[t] = b2[t * 16 + m];
#pragma unroll
        for (int r = 0; r < 4; ++r) {
            float fd = (float)cnt[n0 + kb * 4 + r];
#pragma unroll
            for (int t = 0; t < 3; ++t) acc[t][r] = fmaf(fd, b2j[t], acc[t][r]);
        }
    }

    // ---- transpose C->A (agg), GEMM2: relu(agg @ U1 + ub1)
#pragma unroll
    for (int t = 0; t < 3; ++t)
#pragma unroll
        for (int r = 0; r < 4; ++r)
            tile[wid][kb * 4 + r][t * 16 + m] = acc[t][r];
    asm volatile("s_waitcnt lgkmcnt(0)" ::: "memory");
    {
        const float* row = &tile[wid][m][0];
        *(float4*)(c0)     = *(const float4*)(row + kb * 8);
        *(float4*)(c0 + 4) = *(const float4*)(row + kb * 8 + 4);
        if (kb < 2) {
            *(float4*)(c1)     = *(const float4*)(row + 32 + kb * 8);
            *(float4*)(c1 + 4) = *(const float4*)(row + 32 + kb * 8 + 4);
        } else {
#pragma unroll
            for (int i = 0; i < 8; ++i) c1[i] = 0.0f;
        }
    }
    asm volatile("s_waitcnt lgkmcnt(0)" ::: "memory");   // reads done before overwrite
    split8p(c0, ah0, al0);
    split8p(c1, ah1, al1);
    gemm3(ah0, al0, ah1, al1, u1hi, u1lo, lane, acc);
    {
        float bj[3];
#pragma unroll
        for (int t = 0; t < 3; ++t) bj[t] = ub1[t * 16 + m];
#pragma unroll
        for (int t = 0; t < 3; ++t)
#pragma unroll
            for (int r = 0; r < 4; ++r)
                acc[t][r] = fmaxf(acc[t][r] + bj[t], 0.0f);
    }

    // ---- transpose C->A (t), GEMM3: t @ U2
#pragma unroll
    for (int t = 0; t < 3; ++t)
#pragma unroll
        for (int r = 0; r < 4; ++r)
            tile[wid][kb * 4 + r][t * 16 + m] = acc[t][r];
    asm volatile("s_waitcnt lgkmcnt(0)" ::: "memory");
    {
        const float* row = &tile[wid][m][0];
        *(float4*)(c0)     = *(const float4*)(row + kb * 8);
        *(float4*)(c0 + 4) = *(const float4*)(row + kb * 8 + 4);
        if (kb < 2) {
            *(float4*)(c1)     = *(const float4*)(row + 32 + kb * 8);
            *(float4*)(c1 + 4) = *(const float4*)(row + 32 + kb * 8 + 4);
        } else {
#pragma unroll
            for (int i = 0; i < 8; ++i) c1[i] = 0.0f;
        }
    }
    split8p(c0, ah0, al0);
    split8p(c1, ah1, al1);
    gemm3(ah0, al0, ah1, al1, u2hi, u2lo, lane, acc);

    // ---- out = hin + ub2 + acc ; store (coalesced 64B groups per (r,t))
    {
        float bj[3];
#pragma unroll
        for (int t = 0; t < 3; ++t) bj[t] = ub2[t * 16 + m];
#pragma unroll
        for (int r = 0; r < 4; ++r) {
            const size_t row = (size_t)(n0 + kb * 4 + r) * NE;
#pragma unroll
            for (int t = 0; t < 3; ++t) {
                int j = t * 16 + m;
                hout[row + j] = hin[row + j] + bj[t] + acc[t][r];
            }
        }
    }
}

// ---------------- readout (LDS-staged weights) ----------------
__global__ __launch_bounds__(256, 2) void readout_kernel(const float* __restrict__ h,
                                                         const int* __restrict__ gid,
                                                         const float* __restrict__ w1,  // row-major
                                                         const float* __restrict__ b1,
                                                         const float* __restrict__ w2,  // [48]
                                                         const float* __restrict__ b2,  // [1]
                                                         float* __restrict__ out, int N) {
    __shared__ __align__(16) float sW1[NE * NE], sB1[NE], sW2v[NE];
    for (int i = threadIdx.x; i < NE * NE / 4; i += 256)
        ((float4*)sW1)[i] = ((const float4*)w1)[i];
    if (threadIdx.x < 12)      ((float4*)sB1)[threadIdx.x]       = ((const float4*)b1)[threadIdx.x];
    else if (threadIdx.x < 24) ((float4*)sW2v)[threadIdx.x - 12] = ((const float4*)w2)[threadIdx.x - 12];
    __syncthreads();

    int n = blockIdx.x * 256 + threadIdx.x;
    if (n >= N) return;

    float t[NE];
#pragma unroll
    for (int q = 0; q < 12; ++q) {
        float4 b = ((const float4*)sB1)[q];
        t[4*q+0] = b.x; t[4*q+1] = b.y; t[4*q+2] = b.z; t[4*q+3] = b.w;
    }
    const float4* hp = (const float4*)(h + (size_t)n * NE);
    const float4* W1s = (const float4*)sW1;
    {
        float4 a = hp[0];
#pragma unroll
        for (int q = 0; q < 12; ++q) {
            float4 an;
            if (q < 11) an = hp[q + 1];
            float a0 = a.x, a1 = a.y, a2 = a.z, a3 = a.w;
#pragma unroll
            for (int kk = 0; kk < 4; ++kk) {
                const float xk = (kk == 0) ? a0 : (kk == 1) ? a1 : (kk == 2) ? a2 : a3;
                const int k = 4 * q + kk;
#pragma unroll
                for (int j = 0; j < 12; ++j) {
                    float4 w = W1s[k * 12 + j];
                    t[4*j+0] = fmaf(xk, w.x, t[4*j+0]);
                    t[4*j+1] = fmaf(xk, w.y, t[4*j+1]);
                    t[4*j+2] = fmaf(xk, w.z, t[4*j+2]);
                    t[4*j+3] = fmaf(xk, w.w, t[4*j+3]);
                }
            }
            a = an;
        }
    }
    float y = b2[0];
#pragma unroll
    for (int j = 0; j < NE; ++j) y = fmaf(fmaxf(t[j], 0.0f), sW2v[j], y);
    atomicAdd(out + gid[n], y);
}

extern "C" void kernel_launch(void* const* d_in, const int* in_sizes, int n_in,
                              void* d_out, int out_size, void* d_ws, size_t ws_size,
                              hipStream_t stream) {
    const int*   AtomicNum = (const int*)  d_in[0];
    const int*   Edge      = (const int*)  d_in[1];
    const int*   graph_id  = (const int*)  d_in[2];
    const float* emb       = (const float*)d_in[3];
    const float* msg_w1    = (const float*)d_in[4];
    const float* msg_b1    = (const float*)d_in[5];
    const float* msg_w2    = (const float*)d_in[6];
    const float* msg_b2    = (const float*)d_in[7];
    const float* upd_w1    = (const float*)d_in[8];
    const float* upd_b1    = (const float*)d_in[9];
    const float* upd_w2    = (const float*)d_in[10];
    const float* upd_b2    = (const float*)d_in[11];
    const float* ro_w1     = (const float*)d_in[12];
    const float* ro_b1     = (const float*)d_in[13];
    const float* ro_w2     = (const float*)d_in[14];
    const float* ro_b2     = (const float*)d_in[15];

    const int N = in_sizes[0];          // 100000 (divisible by 16)
    const int E = in_sizes[1] / 2;      // 1600000
    const int* src = Edge;
    const int* dst = Edge + E;

    // workspace layout (~46 MB)
    float*  h    = (float*)d_ws;                       // N*48
    float*  h2   = h  + (size_t)N * NE;                // N*48
    int*    cnt  = (int*)(h2 + (size_t)N * NE);        // N
    int*    offs = cnt + N;                            // N (end offsets after scatter)
    int*    colsrc = offs + N;                         // E
    // 4 packed matrices (msg_w1, msg_w2, upd_w1, upd_w2), each 6*384 short8
    short8* whi  = (short8*)(colsrc + E);              // 4*2304
    short8* wlo  = whi + 4 * 2304;                     // 4*2304

    hipMemsetAsync(d_out, 0, (size_t)out_size * sizeof(float), stream);
    hipMemsetAsync(cnt, 0, (size_t)N * sizeof(int), stream);

    int n4 = N * 12;
    embed_kernel<<<(n4 + 255) / 256, 256, 0, stream>>>(AtomicNum, emb, h, n4);

    hist_kernel<<<(E + 255) / 256, 256, 0, stream>>>(dst, cnt, E);
    scan_kernel<<<1, 1024, 0, stream>>>(cnt, offs, N);
    scatter_kernel<<<(E + 255) / 256, 256, 0, stream>>>(src, dst, offs, colsrc, E);

    const int PK = 6 * 3 * 2 * 64;   // 2304
    pack_w_kernel<<<(PK + 255) / 256, 256, 0, stream>>>(msg_w1, whi + 0 * 2304, wlo + 0 * 2304);
    pack_w_kernel<<<(PK + 255) / 256, 256, 0, stream>>>(msg_w2, whi + 1 * 2304, wlo + 1 * 2304);
    pack_w_kernel<<<(PK + 255) / 256, 256, 0, stream>>>(upd_w1, whi + 2 * 2304, wlo + 2 * 2304);
    pack_w_kernel<<<(PK + 255) / 256, 256, 0, stream>>>(upd_w2, whi + 3 * 2304, wlo + 3 * 2304);

    const float* hin = h;
    float* hout = h2;
    for (int l = 0; l < 6; ++l) {
        edge_kernel<<<(N / 4 + 3) / 4, 256, 0, stream>>>(
            hin, colsrc, offs, cnt, hout,
            whi + 0 * 2304 + (size_t)l * 384, wlo + 0 * 2304 + (size_t)l * 384,
            msg_b1 + (size_t)l * NE,
            N);
        node_kernel<<<(N / 16 + 3) / 4, 256, 0, stream>>>(
            hin, hout, cnt,
            whi + 1 * 2304 + (size_t)l * 384, wlo + 1 * 2304 + (size_t)l * 384, msg_b2 + (size_t)l * NE,
            whi + 2 * 2304 + (size_t)l * 384, wlo + 2 * 2304 + (size_t)l * 384, upd_b1 + (size_t)l * NE,
            whi + 3 * 2304 + (size_t)l * 384, wlo + 3 * 2304 + (size_t)l * 384, upd_b2 + (size_t)l * NE,
            N);
        const float* tmp = hin; hin = hout; hout = (float*)tmp;
    }

    readout_kernel<<<(N + 255) / 256, 256, 0, stream>>>(
        hin, graph_id, ro_w1, ro_b1, ro_w2, ro_b2, (float*)d_out, N);
}